// Round 6
// baseline (943.429 us; speedup 1.0000x reference)
//
#include <hip/hip_runtime.h>
#include <hip/hip_bf16.h>

#define N_ATOMS 100000
#define N_BONDS 200000
#define MAX_NB 6
#define HIDDEN 300
#define HP 320               // padded hidden: row = 640 B = 40 x 16B chunks
#define CH 40
#define ATOM_FD 133
#define BOND_FD 147
#define N_MOLS 5000
#define APM 20

#define NT 20                // 20*16 = 320 output cols (300 real + 20 zero)
#define KK_I 5               // K=160 >= 147
#define KK_H 10              // K=320 >= 300
#define KK_O 14              // K=448 >= 433

using bf16 = __hip_bfloat16;
typedef __attribute__((ext_vector_type(8))) short short8v;
typedef __attribute__((ext_vector_type(4))) float float4v;
typedef unsigned int u32;
typedef unsigned short u16;

__device__ __forceinline__ float us2f(u16 u) {
    union { u32 i; float f; } v; v.i = ((u32)u) << 16; return v.f;
}
__device__ __forceinline__ u16 f2us(float f) {
    bf16 h = __float2bfloat16(f);
    return *(u16*)&h;
}
__device__ __forceinline__ u32 pack2(float a, float b) {
    return (u32)f2us(a) | ((u32)f2us(b) << 16);
}
__device__ __forceinline__ uint2 pack4(const float4v& a) {
    uint2 o; o.x = pack2(a[0], a[1]); o.y = pack2(a[2], a[3]); return o;
}
__device__ __forceinline__ u32 relu2(u32 u) {
    u32 r = (u & 0x80000000u) ? (u & 0x0000ffffu) : u;
    r = (r & 0x8000u) ? (r & 0xffff0000u) : r;
    return r;
}
__device__ __forceinline__ uint4 relu8(uint4 u) {
    u.x = relu2(u.x); u.y = relu2(u.y); u.z = relu2(u.z); u.w = relu2(u.w);
    return u;
}

// ---------------------------------------------------------------------------
// pack_w: W [Ksrc x 300] fp32 -> bf16 MFMA-B fragments [KK][NT][64][8]
// mode==2 (W_o): K layout is [amsg(0..299) | f_atoms(300..432)].
__global__ __launch_bounds__(64) void pack_w(const float* __restrict__ src,
                                             short* __restrict__ dst,
                                             int Ksrc, int mode) {
    int kk = blockIdx.x / NT, nt = blockIdx.x % NT;
    int lane = threadIdx.x;
    int col = nt * 16 + (lane & 15);
#pragma unroll
    for (int j = 0; j < 8; ++j) {
        int k = kk * 32 + (lane >> 4) * 8 + j;
        float v = 0.f;
        if (k < Ksrc && col < HIDDEN) {
            int krow = k;
            if (mode == 2) krow = (k < HIDDEN) ? (ATOM_FD + k) : (k - HIDDEN);
            v = src[krow * HIDDEN + col];
        }
        dst[(((kk * NT + nt) << 6) + lane) * 8 + j] = (short)f2us(v);
    }
}

// ---------------------------------------------------------------------------
// K1: inp = f_bonds @ W_i. 32 rows/block, VGPR-capped for 8 waves/SIMD.
__global__ __launch_bounds__(256, 8) void k1_input(const float* __restrict__ fb,
                                                   const short8v* __restrict__ WiP,
                                                   u16* __restrict__ inp) {
    __shared__ char sm[32 * 640];
    const int tid = threadIdx.x;
    const long base = (long)blockIdx.x * 32;
#pragma unroll 4
    for (int it = 0; it < 20; ++it) {
        int i = tid + it * 256;
        int row = i / 160, c = i % 160;
        float v = (c < BOND_FD) ? fb[(base + row) * BOND_FD + c] : 0.f;
        int byte = row * 320 + c * 2;
        *(u16*)(sm + (byte ^ ((row & 7) << 4))) = f2us(v);
    }
    __syncthreads();

    const int lane = tid & 63, wave = tid >> 6;
    const int nt0 = wave * 5;
    const int arow0 = lane & 15, ahi = lane >> 4;
    float4v acc[5][2];
#pragma unroll
    for (int nt = 0; nt < 5; ++nt)
#pragma unroll
        for (int rg = 0; rg < 2; ++rg) acc[nt][rg] = {0.f, 0.f, 0.f, 0.f};
    for (int kk = 0; kk < KK_I; ++kk) {
        short8v a[2];
#pragma unroll
        for (int rg = 0; rg < 2; ++rg) {
            int row = rg * 16 + arow0;
            int byte = row * 320 + kk * 64 + ahi * 16;
            a[rg] = *(const short8v*)(sm + (byte ^ ((row & 7) << 4)));
        }
#pragma unroll
        for (int nt = 0; nt < 5; ++nt) {
            short8v b = WiP[((kk * NT + nt0 + nt) << 6) + lane];
#pragma unroll
            for (int rg = 0; rg < 2; ++rg)   // swapped: acc = C^T fragments
                acc[nt][rg] = __builtin_amdgcn_mfma_f32_16x16x32_bf16(b, a[rg], acc[nt][rg], 0, 0, 0);
        }
    }
    __syncthreads();
#pragma unroll
    for (int nt = 0; nt < 5; ++nt)
#pragma unroll
        for (int rg = 0; rg < 2; ++rg) {
            int row = rg * 16 + arow0;
            int byte = row * 640 + (nt0 + nt) * 32 + ahi * 8;
            *(uint2*)(sm + (byte ^ ((row & 7) << 4))) = pack4(acc[nt][rg]);
        }
    __syncthreads();
#pragma unroll
    for (int it = 0; it < 5; ++it) {
        int id = tid + it * 256;
        int row = id / CH, c = id % CH;
        int byte = row * 640 + c * 16;
        uint4 v = *(const uint4*)(sm + (byte ^ ((row & 7) << 4)));
        ((uint4*)(inp + (base + row) * HP))[c] = v;
    }
}

// ---------------------------------------------------------------------------
// K2G: dst[a] = sum_j act(src[a2b[a][j]]) — 2 chunks/thread (shared indices,
// 12 outstanding 16B gathers).
template<int RELU>
__global__ __launch_bounds__(256, 8) void k2_gather(const u16* __restrict__ src,
                                                    const int* __restrict__ a2b,
                                                    u16* __restrict__ dst) {
    int id = blockIdx.x * 256 + threadIdx.x;
    int atom = id / 20, c = id % 20;
    if (atom >= N_ATOMS) return;
    const int* nb = a2b + atom * MAX_NB;
    float s[16];
#pragma unroll
    for (int q = 0; q < 16; ++q) s[q] = 0.f;
#pragma unroll
    for (int j = 0; j < MAX_NB; ++j) {
        int b = nb[j];
        const uint4* rp = (const uint4*)(src + (long)b * HP);
        uint4 u0 = rp[c];
        uint4 u1 = rp[c + 20];
        if (RELU) { u0 = relu8(u0); u1 = relu8(u1); }
        s[0] += us2f(u0.x & 0xffff); s[1] += us2f(u0.x >> 16);
        s[2] += us2f(u0.y & 0xffff); s[3] += us2f(u0.y >> 16);
        s[4] += us2f(u0.z & 0xffff); s[5] += us2f(u0.z >> 16);
        s[6] += us2f(u0.w & 0xffff); s[7] += us2f(u0.w >> 16);
        s[8]  += us2f(u1.x & 0xffff); s[9]  += us2f(u1.x >> 16);
        s[10] += us2f(u1.y & 0xffff); s[11] += us2f(u1.y >> 16);
        s[12] += us2f(u1.z & 0xffff); s[13] += us2f(u1.z >> 16);
        s[14] += us2f(u1.w & 0xffff); s[15] += us2f(u1.w >> 16);
    }
    uint4 o0, o1;
    o0.x = pack2(s[0], s[1]);  o0.y = pack2(s[2], s[3]);
    o0.z = pack2(s[4], s[5]);  o0.w = pack2(s[6], s[7]);
    o1.x = pack2(s[8], s[9]);  o1.y = pack2(s[10], s[11]);
    o1.z = pack2(s[12], s[13]); o1.w = pack2(s[14], s[15]);
    uint4* dp = (uint4*)(dst + (long)atom * HP);
    dp[c] = o0;
    dp[c + 20] = o1;
}

// ---------------------------------------------------------------------------
// KZF: msg_out = relu(inp + (AM[b2a] - act(msgsrc[b2revb])) @ W_h)
// Fused gather-diff stage; +inp folded into epilogue (keeps VGPR <= 64).
template<int RELUREV>
__global__ __launch_bounds__(256, 8) void kzf_update(const u16* __restrict__ inp,
                                                     const u16* __restrict__ AM,
                                                     const u16* __restrict__ msgsrc,
                                                     const int* __restrict__ b2a,
                                                     const int* __restrict__ b2revb,
                                                     const short8v* __restrict__ WhP,
                                                     u16* __restrict__ msgdst) {
    __shared__ char sm[32 * 640];
    const int tid = threadIdx.x;
    const long base = (long)blockIdx.x * 32;
    const int lane = tid & 63, wave = tid >> 6;
    const int nt0 = wave * 5;
    const int arow0 = lane & 15, ahi = lane >> 4;

    // stage: m = AM[b2a[row]] - act(msgsrc[b2revb[row]]) into LDS
#pragma unroll
    for (int it = 0; it < 5; ++it) {
        int i = tid + it * 256;
        int row = i / CH, c = i % CH;
        long b = base + row;
        int ia = b2a[b], ir = b2revb[b];
        uint4 ua = ((const uint4*)(AM + (long)ia * HP))[c];
        uint4 uz = ((const uint4*)(msgsrc + (long)ir * HP))[c];
        if (RELUREV) uz = relu8(uz);
        uint4 o;
#define EL(w) o.w = pack2(us2f(ua.w & 0xffff) - us2f(uz.w & 0xffff), \
                          us2f(ua.w >> 16)    - us2f(uz.w >> 16));
        EL(x) EL(y) EL(z) EL(w)
#undef EL
        int byte = row * 640 + c * 16;
        *(uint4*)(sm + (byte ^ ((row & 7) << 4))) = o;
    }
    __syncthreads();

    float4v acc[5][2];
#pragma unroll
    for (int nt = 0; nt < 5; ++nt)
#pragma unroll
        for (int rg = 0; rg < 2; ++rg) acc[nt][rg] = {0.f, 0.f, 0.f, 0.f};
    for (int kk = 0; kk < KK_H; ++kk) {
        short8v a[2];
#pragma unroll
        for (int rg = 0; rg < 2; ++rg) {
            int row = rg * 16 + arow0;
            int byte = row * 640 + kk * 64 + ahi * 16;
            a[rg] = *(const short8v*)(sm + (byte ^ ((row & 7) << 4)));
        }
#pragma unroll
        for (int nt = 0; nt < 5; ++nt) {
            short8v b = WhP[((kk * NT + nt0 + nt) << 6) + lane];
#pragma unroll
            for (int rg = 0; rg < 2; ++rg)
                acc[nt][rg] = __builtin_amdgcn_mfma_f32_16x16x32_bf16(b, a[rg], acc[nt][rg], 0, 0, 0);
        }
    }
    __syncthreads();
#pragma unroll
    for (int nt = 0; nt < 5; ++nt)
#pragma unroll
        for (int rg = 0; rg < 2; ++rg) {
            int row = rg * 16 + arow0;
            uint2 u = *(const uint2*)(inp + (base + row) * HP
                                      + (nt0 + nt) * 16 + ahi * 4);
            float4v v;
            v[0] = fmaxf(acc[nt][rg][0] + us2f(u.x & 0xffff), 0.f);
            v[1] = fmaxf(acc[nt][rg][1] + us2f(u.x >> 16), 0.f);
            v[2] = fmaxf(acc[nt][rg][2] + us2f(u.y & 0xffff), 0.f);
            v[3] = fmaxf(acc[nt][rg][3] + us2f(u.y >> 16), 0.f);
            int byte = row * 640 + (nt0 + nt) * 32 + ahi * 8;
            *(uint2*)(sm + (byte ^ ((row & 7) << 4))) = pack4(v);
        }
    __syncthreads();
#pragma unroll
    for (int it = 0; it < 5; ++it) {
        int id = tid + it * 256;
        int row = id / CH, c = id % CH;
        int byte = row * 640 + c * 16;
        uint4 v = *(const uint4*)(sm + (byte ^ ((row & 7) << 4)));
        ((uint4*)(msgdst + (base + row) * HP))[c] = v;
    }
}

// ---------------------------------------------------------------------------
// K4: fused readout + pool. 80 atoms = 4 molecules per block.
__global__ __launch_bounds__(256) void k4_readout(const float* __restrict__ fa,
                                                  const u16* __restrict__ AM,
                                                  const short8v* __restrict__ WoP,
                                                  const float* __restrict__ bo,
                                                  float* __restrict__ out) {
    __shared__ char sm[80 * 896];
    const int tid = threadIdx.x;
    const long base = (long)blockIdx.x * 80;
    for (int i = tid; i < 80 * 75; i += 256) {   // amsg cols 0..299
        int row = i / 75, c = i % 75;
        uint2 o = ((const uint2*)(AM + (base + row) * HP))[c];
        int byte = row * 896 + c * 8;
        *(uint2*)(sm + (byte ^ ((row & 7) << 4))) = o;
    }
    for (int i = tid; i < 80 * 148; i += 256) {  // f_atoms cols 300..432 + pad
        int row = i / 148, c2 = i % 148;
        float v = (c2 < ATOM_FD) ? fa[(base + row) * ATOM_FD + c2] : 0.f;
        int byte = row * 896 + (HIDDEN + c2) * 2;
        *(u16*)(sm + (byte ^ ((row & 7) << 4))) = f2us(v);
    }
    __syncthreads();

    const int lane = tid & 63, wave = tid >> 6;
    const int nt0 = wave * 5;
    const int arow0 = lane & 15, ahi = lane >> 4;
    float4v acc[5][5];
#pragma unroll
    for (int nt = 0; nt < 5; ++nt)
#pragma unroll
        for (int rg = 0; rg < 5; ++rg) acc[nt][rg] = {0.f, 0.f, 0.f, 0.f};
    for (int kk = 0; kk < KK_O; ++kk) {
        short8v a[5];
#pragma unroll
        for (int rg = 0; rg < 5; ++rg) {
            int row = rg * 16 + arow0;
            int byte = row * 896 + kk * 64 + ahi * 16;
            a[rg] = *(const short8v*)(sm + (byte ^ ((row & 7) << 4)));
        }
#pragma unroll
        for (int nt = 0; nt < 5; ++nt) {
            short8v b = WoP[((kk * NT + nt0 + nt) << 6) + lane];
#pragma unroll
            for (int rg = 0; rg < 5; ++rg)
                acc[nt][rg] = __builtin_amdgcn_mfma_f32_16x16x32_bf16(b, a[rg], acc[nt][rg], 0, 0, 0);
        }
    }
    __syncthreads();
#pragma unroll
    for (int nt = 0; nt < 5; ++nt) {
        int colb = (nt0 + nt) * 16 + ahi * 4;
        float bias[4];
#pragma unroll
        for (int q = 0; q < 4; ++q)
            bias[q] = (colb + q < HIDDEN) ? bo[colb + q] : 0.f;
#pragma unroll
        for (int rg = 0; rg < 5; ++rg) {
            int row = rg * 16 + arow0;
            float4v v;
#pragma unroll
            for (int q = 0; q < 4; ++q) v[q] = fmaxf(acc[nt][rg][q] + bias[q], 0.f);
            int byte = row * 640 + (nt0 + nt) * 32 + ahi * 8;
            *(uint2*)(sm + (byte ^ ((row & 7) << 4))) = pack4(v);
        }
    }
    __syncthreads();
    // pool: 4 molecules x 300 cols, mean over 20 rows each
    for (int idx = tid; idx < 4 * HIDDEN; idx += 256) {
        int m = idx / HIDDEN, col = idx % HIDDEN;
        float s = 0.f;
#pragma unroll
        for (int r = 0; r < APM; ++r) {
            int row = m * APM + r;
            int byte = row * 640 + col * 2;
            s += us2f(*(const u16*)(sm + (byte ^ ((row & 7) << 4))));
        }
        out[((long)blockIdx.x * 4 + m) * HIDDEN + col] = s * (1.f / APM);
    }
}

// ---------------------------------------------------------------------------
extern "C" void kernel_launch(void* const* d_in, const int* in_sizes, int n_in,
                              void* d_out, int out_size, void* d_ws, size_t ws_size,
                              hipStream_t stream) {
    const float* f_atoms = (const float*)d_in[0];
    const float* f_bonds = (const float*)d_in[1];
    const int* a2b = (const int*)d_in[2];
    const int* b2a = (const int*)d_in[3];
    const int* b2revb = (const int*)d_in[4];
    const float* Wi = (const float*)d_in[6];
    const float* Wh = (const float*)d_in[7];
    const float* Wo = (const float*)d_in[8];
    const float* bo = (const float*)d_in[9];
    float* out = (float*)d_out;

    char* ws = (char*)d_ws;
    size_t off = 0;
    auto alloc = [&](size_t bytes) {
        void* p = ws + off;
        off = (off + bytes + 255) & ~(size_t)255;
        return p;
    };
    u16* inp  = (u16*)alloc((size_t)N_BONDS * HP * sizeof(u16));   // 128 MB
    u16* msgA = (u16*)alloc((size_t)N_BONDS * HP * sizeof(u16));   // 128 MB
    u16* msgB = (u16*)alloc((size_t)N_BONDS * HP * sizeof(u16));   // 128 MB
    u16* AM   = (u16*)alloc((size_t)N_ATOMS * HP * sizeof(u16));   //  64 MB
    short* WiP = (short*)alloc((size_t)KK_I * NT * 64 * 8 * sizeof(short));
    short* WhP = (short*)alloc((size_t)KK_H * NT * 64 * 8 * sizeof(short));
    short* WoP = (short*)alloc((size_t)KK_O * NT * 64 * 8 * sizeof(short));

    pack_w<<<KK_I * NT, 64, 0, stream>>>(Wi, WiP, BOND_FD, 0);
    pack_w<<<KK_H * NT, 64, 0, stream>>>(Wh, WhP, HIDDEN, 0);
    pack_w<<<KK_O * NT, 64, 0, stream>>>(Wo, WoP, ATOM_FD + HIDDEN, 2);

    k1_input<<<N_BONDS / 32, 256, 0, stream>>>(f_bonds, (const short8v*)WiP, inp);

    const int g2 = (N_ATOMS * 20 + 255) / 256;
    // iter 1: msg0 = relu(inp) applied on the fly
    k2_gather<1><<<g2, 256, 0, stream>>>(inp, a2b, AM);
    kzf_update<1><<<N_BONDS / 32, 256, 0, stream>>>(inp, AM, inp, b2a, b2revb,
                                                    (const short8v*)WhP, msgA);
    // iter 2
    k2_gather<0><<<g2, 256, 0, stream>>>(msgA, a2b, AM);
    kzf_update<0><<<N_BONDS / 32, 256, 0, stream>>>(inp, AM, msgA, b2a, b2revb,
                                                    (const short8v*)WhP, msgB);
    // readout + pool
    k2_gather<0><<<g2, 256, 0, stream>>>(msgB, a2b, AM);
    k4_readout<<<N_ATOMS / 80, 256, 0, stream>>>(f_atoms, AM,
                                                 (const short8v*)WoP, bo, out);
}

// Round 7
// 827.894 us; speedup vs baseline: 1.1396x; 1.1396x over previous
//
#include <hip/hip_runtime.h>
#include <hip/hip_bf16.h>

#define N_ATOMS 100000
#define N_BONDS 200000
#define MAX_NB 6
#define HIDDEN 300
#define HP 320               // padded hidden: row = 640 B = 40 x 16B chunks
#define CH 40
#define ATOM_FD 133
#define BOND_FD 147
#define N_MOLS 5000
#define APM 20

#define NT 20                // 20*16 = 320 output cols (300 real + 20 zero)
#define KK_I 5               // K=160 >= 147
#define KK_H 10              // K=320 >= 300
#define KK_O 14              // K=448 >= 433

using bf16 = __hip_bfloat16;
typedef __attribute__((ext_vector_type(8))) short short8v;
typedef __attribute__((ext_vector_type(4))) float float4v;
typedef unsigned int u32;
typedef unsigned short u16;

__device__ __forceinline__ float us2f(u16 u) {
    union { u32 i; float f; } v; v.i = ((u32)u) << 16; return v.f;
}
__device__ __forceinline__ u16 f2us(float f) {
    bf16 h = __float2bfloat16(f);
    return *(u16*)&h;
}
__device__ __forceinline__ u32 pack2(float a, float b) {
    return (u32)f2us(a) | ((u32)f2us(b) << 16);
}
__device__ __forceinline__ uint2 pack4(const float4v& a) {
    uint2 o; o.x = pack2(a[0], a[1]); o.y = pack2(a[2], a[3]); return o;
}
__device__ __forceinline__ u32 relu2(u32 u) {
    u32 r = (u & 0x80000000u) ? (u & 0x0000ffffu) : u;
    r = (r & 0x8000u) ? (r & 0xffff0000u) : r;
    return r;
}
__device__ __forceinline__ uint4 relu8(uint4 u) {
    u.x = relu2(u.x); u.y = relu2(u.y); u.z = relu2(u.z); u.w = relu2(u.w);
    return u;
}

// ---------------------------------------------------------------------------
// pack_w: W [Ksrc x 300] fp32 -> bf16 MFMA-B fragments [KK][NT][64][8]
// mode==2 (W_o): K layout is [amsg(0..299) | f_atoms(300..432)].
__global__ __launch_bounds__(64) void pack_w(const float* __restrict__ src,
                                             short* __restrict__ dst,
                                             int Ksrc, int mode) {
    int kk = blockIdx.x / NT, nt = blockIdx.x % NT;
    int lane = threadIdx.x;
    int col = nt * 16 + (lane & 15);
#pragma unroll
    for (int j = 0; j < 8; ++j) {
        int k = kk * 32 + (lane >> 4) * 8 + j;
        float v = 0.f;
        if (k < Ksrc && col < HIDDEN) {
            int krow = k;
            if (mode == 2) krow = (k < HIDDEN) ? (ATOM_FD + k) : (k - HIDDEN);
            v = src[krow * HIDDEN + col];
        }
        dst[(((kk * NT + nt) << 6) + lane) * 8 + j] = (short)f2us(v);
    }
}

// ---------------------------------------------------------------------------
// K1: inp = f_bonds @ W_i. 32 rows/block, 512 threads (8 waves), each wave
// owns 5 nt-tiles x 16 rows -> acc[5] = 20 VGPRs.
__global__ __launch_bounds__(512, 8) void k1_input(const float* __restrict__ fb,
                                                   const short8v* __restrict__ WiP,
                                                   u16* __restrict__ inp) {
    __shared__ char sm[32 * 640];
    const int tid = threadIdx.x;
    const long base = (long)blockIdx.x * 32;
#pragma unroll
    for (int it = 0; it < 10; ++it) {
        int i = tid + it * 512;
        int row = i / 160, c = i % 160;
        float v = (c < BOND_FD) ? fb[(base + row) * BOND_FD + c] : 0.f;
        int byte = row * 320 + c * 2;
        *(u16*)(sm + (byte ^ ((row & 7) << 4))) = f2us(v);
    }
    __syncthreads();

    const int lane = tid & 63, wave = tid >> 6;
    const int rg = wave >> 2;           // row-group 0..1
    const int nt0 = (wave & 3) * 5;     // col-tile base
    const int arow0 = lane & 15, ahi = lane >> 4;
    const int row = rg * 16 + arow0;
    float4v acc[5];
#pragma unroll
    for (int nt = 0; nt < 5; ++nt) acc[nt] = {0.f, 0.f, 0.f, 0.f};
    for (int kk = 0; kk < KK_I; ++kk) {
        int byte = row * 320 + kk * 64 + ahi * 16;
        short8v a = *(const short8v*)(sm + (byte ^ ((row & 7) << 4)));
#pragma unroll
        for (int nt = 0; nt < 5; ++nt) {
            short8v b = WiP[((kk * NT + nt0 + nt) << 6) + lane];
            acc[nt] = __builtin_amdgcn_mfma_f32_16x16x32_bf16(b, a, acc[nt], 0, 0, 0);
        }
    }
    __syncthreads();
#pragma unroll
    for (int nt = 0; nt < 5; ++nt) {
        int byte = row * 640 + (nt0 + nt) * 32 + ahi * 8;
        *(uint2*)(sm + (byte ^ ((row & 7) << 4))) = pack4(acc[nt]);
    }
    __syncthreads();
#pragma unroll
    for (int it = 0; it < 3; ++it) {
        int i = tid + it * 512;
        if (i < 1280) {
            int r = i / CH, c = i % CH;
            int byte = r * 640 + c * 16;
            uint4 v = *(const uint4*)(sm + (byte ^ ((r & 7) << 4)));
            ((uint4*)(inp + (base + r) * HP))[c] = v;
        }
    }
}

// ---------------------------------------------------------------------------
// K2G: dst[a] = sum_j act(src[a2b[a][j]]) — 2 chunks/thread (shared indices).
template<int RELU>
__global__ __launch_bounds__(256, 8) void k2_gather(const u16* __restrict__ src,
                                                    const int* __restrict__ a2b,
                                                    u16* __restrict__ dst) {
    int id = blockIdx.x * 256 + threadIdx.x;
    int atom = id / 20, c = id % 20;
    if (atom >= N_ATOMS) return;
    const int* nb = a2b + atom * MAX_NB;
    float s[16];
#pragma unroll
    for (int q = 0; q < 16; ++q) s[q] = 0.f;
#pragma unroll
    for (int j = 0; j < MAX_NB; ++j) {
        int b = nb[j];
        const uint4* rp = (const uint4*)(src + (long)b * HP);
        uint4 u0 = rp[c];
        uint4 u1 = rp[c + 20];
        if (RELU) { u0 = relu8(u0); u1 = relu8(u1); }
        s[0] += us2f(u0.x & 0xffff); s[1] += us2f(u0.x >> 16);
        s[2] += us2f(u0.y & 0xffff); s[3] += us2f(u0.y >> 16);
        s[4] += us2f(u0.z & 0xffff); s[5] += us2f(u0.z >> 16);
        s[6] += us2f(u0.w & 0xffff); s[7] += us2f(u0.w >> 16);
        s[8]  += us2f(u1.x & 0xffff); s[9]  += us2f(u1.x >> 16);
        s[10] += us2f(u1.y & 0xffff); s[11] += us2f(u1.y >> 16);
        s[12] += us2f(u1.z & 0xffff); s[13] += us2f(u1.z >> 16);
        s[14] += us2f(u1.w & 0xffff); s[15] += us2f(u1.w >> 16);
    }
    uint4 o0, o1;
    o0.x = pack2(s[0], s[1]);  o0.y = pack2(s[2], s[3]);
    o0.z = pack2(s[4], s[5]);  o0.w = pack2(s[6], s[7]);
    o1.x = pack2(s[8], s[9]);  o1.y = pack2(s[10], s[11]);
    o1.z = pack2(s[12], s[13]); o1.w = pack2(s[14], s[15]);
    uint4* dp = (uint4*)(dst + (long)atom * HP);
    dp[c] = o0;
    dp[c + 20] = o1;
}

// ---------------------------------------------------------------------------
// KZF: msg_out = relu(inp + (AM[b2a] - act(msgsrc[b2revb])) @ W_h)
// 32 rows/block, 512 threads (8 waves), acc[5] = 20 VGPRs per wave.
template<int RELUREV>
__global__ __launch_bounds__(512, 8) void kzf_update(const u16* __restrict__ inp,
                                                     const u16* __restrict__ AM,
                                                     const u16* __restrict__ msgsrc,
                                                     const int* __restrict__ b2a,
                                                     const int* __restrict__ b2revb,
                                                     const short8v* __restrict__ WhP,
                                                     u16* __restrict__ msgdst) {
    __shared__ char sm[32 * 640];
    const int tid = threadIdx.x;
    const long base = (long)blockIdx.x * 32;
    const int lane = tid & 63, wave = tid >> 6;
    const int rg = wave >> 2;
    const int nt0 = (wave & 3) * 5;
    const int arow0 = lane & 15, ahi = lane >> 4;
    const int row = rg * 16 + arow0;

    // stage: m = AM[b2a[row]] - act(msgsrc[b2revb[row]]) into LDS
#pragma unroll
    for (int it = 0; it < 3; ++it) {
        int i = tid + it * 512;
        if (i < 1280) {
            int r = i / CH, c = i % CH;
            long b = base + r;
            int ia = b2a[b], ir = b2revb[b];
            uint4 ua = ((const uint4*)(AM + (long)ia * HP))[c];
            uint4 uz = ((const uint4*)(msgsrc + (long)ir * HP))[c];
            if (RELUREV) uz = relu8(uz);
            uint4 o;
#define EL(w) o.w = pack2(us2f(ua.w & 0xffff) - us2f(uz.w & 0xffff), \
                          us2f(ua.w >> 16)    - us2f(uz.w >> 16));
            EL(x) EL(y) EL(z) EL(w)
#undef EL
            int byte = r * 640 + c * 16;
            *(uint4*)(sm + (byte ^ ((r & 7) << 4))) = o;
        }
    }
    __syncthreads();

    float4v acc[5];
#pragma unroll
    for (int nt = 0; nt < 5; ++nt) acc[nt] = {0.f, 0.f, 0.f, 0.f};
    for (int kk = 0; kk < KK_H; ++kk) {
        int byte = row * 640 + kk * 64 + ahi * 16;
        short8v a = *(const short8v*)(sm + (byte ^ ((row & 7) << 4)));
#pragma unroll
        for (int nt = 0; nt < 5; ++nt) {
            short8v b = WhP[((kk * NT + nt0 + nt) << 6) + lane];
            acc[nt] = __builtin_amdgcn_mfma_f32_16x16x32_bf16(b, a, acc[nt], 0, 0, 0);
        }
    }
    __syncthreads();
#pragma unroll
    for (int nt = 0; nt < 5; ++nt) {
        uint2 u = *(const uint2*)(inp + (base + row) * HP + (nt0 + nt) * 16 + ahi * 4);
        float4v v;
        v[0] = fmaxf(acc[nt][0] + us2f(u.x & 0xffff), 0.f);
        v[1] = fmaxf(acc[nt][1] + us2f(u.x >> 16), 0.f);
        v[2] = fmaxf(acc[nt][2] + us2f(u.y & 0xffff), 0.f);
        v[3] = fmaxf(acc[nt][3] + us2f(u.y >> 16), 0.f);
        int byte = row * 640 + (nt0 + nt) * 32 + ahi * 8;
        *(uint2*)(sm + (byte ^ ((row & 7) << 4))) = pack4(v);
    }
    __syncthreads();
#pragma unroll
    for (int it = 0; it < 3; ++it) {
        int i = tid + it * 512;
        if (i < 1280) {
            int r = i / CH, c = i % CH;
            int byte = r * 640 + c * 16;
            uint4 v = *(const uint4*)(sm + (byte ^ ((r & 7) << 4)));
            ((uint4*)(msgdst + (base + r) * HP))[c] = v;
        }
    }
}

// ---------------------------------------------------------------------------
// K4: fused readout + pool. 80 atoms = 4 molecules per block.
__global__ __launch_bounds__(256) void k4_readout(const float* __restrict__ fa,
                                                  const u16* __restrict__ AM,
                                                  const short8v* __restrict__ WoP,
                                                  const float* __restrict__ bo,
                                                  float* __restrict__ out) {
    __shared__ char sm[80 * 896];
    const int tid = threadIdx.x;
    const long base = (long)blockIdx.x * 80;
    for (int i = tid; i < 80 * 75; i += 256) {   // amsg cols 0..299
        int row = i / 75, c = i % 75;
        uint2 o = ((const uint2*)(AM + (base + row) * HP))[c];
        int byte = row * 896 + c * 8;
        *(uint2*)(sm + (byte ^ ((row & 7) << 4))) = o;
    }
    for (int i = tid; i < 80 * 148; i += 256) {  // f_atoms cols 300..432 + pad
        int row = i / 148, c2 = i % 148;
        float v = (c2 < ATOM_FD) ? fa[(base + row) * ATOM_FD + c2] : 0.f;
        int byte = row * 896 + (HIDDEN + c2) * 2;
        *(u16*)(sm + (byte ^ ((row & 7) << 4))) = f2us(v);
    }
    __syncthreads();

    const int lane = tid & 63, wave = tid >> 6;
    const int nt0 = wave * 5;
    const int arow0 = lane & 15, ahi = lane >> 4;
    float4v acc[5][5];
#pragma unroll
    for (int nt = 0; nt < 5; ++nt)
#pragma unroll
        for (int rg = 0; rg < 5; ++rg) acc[nt][rg] = {0.f, 0.f, 0.f, 0.f};
    for (int kk = 0; kk < KK_O; ++kk) {
        short8v a[5];
#pragma unroll
        for (int rg = 0; rg < 5; ++rg) {
            int row = rg * 16 + arow0;
            int byte = row * 896 + kk * 64 + ahi * 16;
            a[rg] = *(const short8v*)(sm + (byte ^ ((row & 7) << 4)));
        }
#pragma unroll
        for (int nt = 0; nt < 5; ++nt) {
            short8v b = WoP[((kk * NT + nt0 + nt) << 6) + lane];
#pragma unroll
            for (int rg = 0; rg < 5; ++rg)
                acc[nt][rg] = __builtin_amdgcn_mfma_f32_16x16x32_bf16(b, a[rg], acc[nt][rg], 0, 0, 0);
        }
    }
    __syncthreads();
#pragma unroll
    for (int nt = 0; nt < 5; ++nt) {
        int colb = (nt0 + nt) * 16 + ahi * 4;
        float bias[4];
#pragma unroll
        for (int q = 0; q < 4; ++q)
            bias[q] = (colb + q < HIDDEN) ? bo[colb + q] : 0.f;
#pragma unroll
        for (int rg = 0; rg < 5; ++rg) {
            int row = rg * 16 + arow0;
            float4v v;
#pragma unroll
            for (int q = 0; q < 4; ++q) v[q] = fmaxf(acc[nt][rg][q] + bias[q], 0.f);
            int byte = row * 640 + (nt0 + nt) * 32 + ahi * 8;
            *(uint2*)(sm + (byte ^ ((row & 7) << 4))) = pack4(v);
        }
    }
    __syncthreads();
    // pool: 4 molecules x 300 cols, mean over 20 rows each
    for (int idx = tid; idx < 4 * HIDDEN; idx += 256) {
        int m = idx / HIDDEN, col = idx % HIDDEN;
        float s = 0.f;
#pragma unroll
        for (int r = 0; r < APM; ++r) {
            int row = m * APM + r;
            int byte = row * 640 + col * 2;
            s += us2f(*(const u16*)(sm + (byte ^ ((row & 7) << 4))));
        }
        out[((long)blockIdx.x * 4 + m) * HIDDEN + col] = s * (1.f / APM);
    }
}

// ---------------------------------------------------------------------------
extern "C" void kernel_launch(void* const* d_in, const int* in_sizes, int n_in,
                              void* d_out, int out_size, void* d_ws, size_t ws_size,
                              hipStream_t stream) {
    const float* f_atoms = (const float*)d_in[0];
    const float* f_bonds = (const float*)d_in[1];
    const int* a2b = (const int*)d_in[2];
    const int* b2a = (const int*)d_in[3];
    const int* b2revb = (const int*)d_in[4];
    const float* Wi = (const float*)d_in[6];
    const float* Wh = (const float*)d_in[7];
    const float* Wo = (const float*)d_in[8];
    const float* bo = (const float*)d_in[9];
    float* out = (float*)d_out;

    char* ws = (char*)d_ws;
    size_t off = 0;
    auto alloc = [&](size_t bytes) {
        void* p = ws + off;
        off = (off + bytes + 255) & ~(size_t)255;
        return p;
    };
    u16* inp  = (u16*)alloc((size_t)N_BONDS * HP * sizeof(u16));   // 128 MB
    u16* msgA = (u16*)alloc((size_t)N_BONDS * HP * sizeof(u16));   // 128 MB
    u16* msgB = (u16*)alloc((size_t)N_BONDS * HP * sizeof(u16));   // 128 MB
    u16* AM   = (u16*)alloc((size_t)N_ATOMS * HP * sizeof(u16));   //  64 MB
    short* WiP = (short*)alloc((size_t)KK_I * NT * 64 * 8 * sizeof(short));
    short* WhP = (short*)alloc((size_t)KK_H * NT * 64 * 8 * sizeof(short));
    short* WoP = (short*)alloc((size_t)KK_O * NT * 64 * 8 * sizeof(short));

    pack_w<<<KK_I * NT, 64, 0, stream>>>(Wi, WiP, BOND_FD, 0);
    pack_w<<<KK_H * NT, 64, 0, stream>>>(Wh, WhP, HIDDEN, 0);
    pack_w<<<KK_O * NT, 64, 0, stream>>>(Wo, WoP, ATOM_FD + HIDDEN, 2);

    k1_input<<<N_BONDS / 32, 512, 0, stream>>>(f_bonds, (const short8v*)WiP, inp);

    const int g2 = (N_ATOMS * 20 + 255) / 256;
    // iter 1: msg0 = relu(inp) applied on the fly
    k2_gather<1><<<g2, 256, 0, stream>>>(inp, a2b, AM);
    kzf_update<1><<<N_BONDS / 32, 512, 0, stream>>>(inp, AM, inp, b2a, b2revb,
                                                    (const short8v*)WhP, msgA);
    // iter 2
    k2_gather<0><<<g2, 256, 0, stream>>>(msgA, a2b, AM);
    kzf_update<0><<<N_BONDS / 32, 512, 0, stream>>>(inp, AM, msgA, b2a, b2revb,
                                                    (const short8v*)WhP, msgB);
    // readout + pool
    k2_gather<0><<<g2, 256, 0, stream>>>(msgB, a2b, AM);
    k4_readout<<<N_ATOMS / 80, 256, 0, stream>>>(f_atoms, AM,
                                                 (const short8v*)WoP, bo, out);
}

// Round 9
// 657.032 us; speedup vs baseline: 1.4359x; 1.2601x over previous
//
#include <hip/hip_runtime.h>
#include <hip/hip_bf16.h>
#include <hip/hip_fp8.h>

#define N_ATOMS 100000
#define N_BONDS 200000
#define MAX_NB 6
#define HIDDEN 300
#define HP 320               // padded hidden: bf16 row = 640 B; fp8 row = 320 B
#define CH 40
#define ATOM_FD 133
#define BOND_FD 147
#define N_MOLS 5000
#define APM 20

#define NT 20                // 20*16 = 320 output cols (300 real + 20 zero)
#define KK_I 5               // K=160 >= 147
#define KK_H 10              // K=320 >= 300
#define KK_O 14              // K=448 >= 433

using bf16 = __hip_bfloat16;
typedef __attribute__((ext_vector_type(8))) short short8v;
typedef __attribute__((ext_vector_type(4))) float float4v;
typedef unsigned int u32;
typedef unsigned short u16;
typedef unsigned char u8;

__device__ __forceinline__ float us2f(u16 u) {
    union { u32 i; float f; } v; v.i = ((u32)u) << 16; return v.f;
}
__device__ __forceinline__ u16 f2us(float f) {
    bf16 h = __float2bfloat16(f);
    return *(u16*)&h;
}
__device__ __forceinline__ u32 pack2(float a, float b) {
    return (u32)f2us(a) | ((u32)f2us(b) << 16);
}
__device__ __forceinline__ uint2 pack4(const float4v& a) {
    uint2 o; o.x = pack2(a[0], a[1]); o.y = pack2(a[2], a[3]); return o;
}
__device__ __forceinline__ u32 relu2(u32 u) {
    u32 r = (u & 0x80000000u) ? (u & 0x0000ffffu) : u;
    r = (r & 0x8000u) ? (r & 0xffff0000u) : r;
    return r;
}
__device__ __forceinline__ uint4 relu8(uint4 u) {
    u.x = relu2(u.x); u.y = relu2(u.y); u.z = relu2(u.z); u.w = relu2(u.w);
    return u;
}

// ---- fp8 e4m3 (OCP on gfx950) conversion helpers -------------------------
#if defined(__has_builtin)
#if __has_builtin(__builtin_amdgcn_cvt_f32_fp8) && __has_builtin(__builtin_amdgcn_cvt_pk_fp8_f32)
#define HW_FP8 1
#endif
#endif

__device__ __forceinline__ void f8x4_to_f32(u32 p, float* o) {
#ifdef HW_FP8
    o[0] = __builtin_amdgcn_cvt_f32_fp8(p, 0);
    o[1] = __builtin_amdgcn_cvt_f32_fp8(p, 1);
    o[2] = __builtin_amdgcn_cvt_f32_fp8(p, 2);
    o[3] = __builtin_amdgcn_cvt_f32_fp8(p, 3);
#else
#pragma unroll
    for (int i = 0; i < 4; ++i) {
        __hip_fp8_e4m3 h; h.__x = (u8)(p >> (8 * i));
        o[i] = (float)h;
    }
#endif
}
__device__ __forceinline__ u32 f32x4_to_f8(float a, float b, float c, float d) {
#ifdef HW_FP8
    u32 r = __builtin_amdgcn_cvt_pk_fp8_f32(a, b, 0u, false);
    r = __builtin_amdgcn_cvt_pk_fp8_f32(c, d, r, true);
    return r;
#else
    __hip_fp8_e4m3 ha(a), hb(b), hc(c), hd(d);
    return (u32)ha.__x | ((u32)hb.__x << 8) | ((u32)hc.__x << 16) | ((u32)hd.__x << 24);
#endif
}
__device__ __forceinline__ void f8x16_to_f32(uint4 u, float* o) {
    f8x4_to_f32(u.x, o); f8x4_to_f32(u.y, o + 4);
    f8x4_to_f32(u.z, o + 8); f8x4_to_f32(u.w, o + 12);
}

// ---------------------------------------------------------------------------
// pack_w: W [Ksrc x 300] fp32 -> bf16 MFMA-B fragments [KK][NT][64][8]
// mode==2 (W_o): K layout is [amsg(0..299) | f_atoms(300..432)].
__global__ __launch_bounds__(64) void pack_w(const float* __restrict__ src,
                                             short* __restrict__ dst,
                                             int Ksrc, int mode) {
    int kk = blockIdx.x / NT, nt = blockIdx.x % NT;
    int lane = threadIdx.x;
    int col = nt * 16 + (lane & 15);
#pragma unroll
    for (int j = 0; j < 8; ++j) {
        int k = kk * 32 + (lane >> 4) * 8 + j;
        float v = 0.f;
        if (k < Ksrc && col < HIDDEN) {
            int krow = k;
            if (mode == 2) krow = (k < HIDDEN) ? (ATOM_FD + k) : (k - HIDDEN);
            v = src[krow * HIDDEN + col];
        }
        dst[(((kk * NT + nt) << 6) + lane) * 8 + j] = (short)f2us(v);
    }
}

// ---------------------------------------------------------------------------
// K1: inp = f_bonds @ W_i (bf16 out). 32 rows/block, 512 threads, acc[5].
__global__ __launch_bounds__(512, 8) void k1_input(const float* __restrict__ fb,
                                                   const short8v* __restrict__ WiP,
                                                   u16* __restrict__ inp) {
    __shared__ __align__(16) char sm[32 * 640];
    const int tid = threadIdx.x;
    const long base = (long)blockIdx.x * 32;
#pragma unroll
    for (int it = 0; it < 10; ++it) {
        int i = tid + it * 512;
        int row = i / 160, c = i % 160;
        float v = (c < BOND_FD) ? fb[(base + row) * BOND_FD + c] : 0.f;
        int byte = row * 320 + c * 2;
        *(u16*)(sm + (byte ^ ((row & 7) << 4))) = f2us(v);
    }
    __syncthreads();

    const int lane = tid & 63, wave = tid >> 6;
    const int rg = wave >> 2;
    const int nt0 = (wave & 3) * 5;
    const int arow0 = lane & 15, ahi = lane >> 4;
    const int row = rg * 16 + arow0;
    float4v acc[5];
#pragma unroll
    for (int nt = 0; nt < 5; ++nt) acc[nt] = {0.f, 0.f, 0.f, 0.f};
    for (int kk = 0; kk < KK_I; ++kk) {
        int byte = row * 320 + kk * 64 + ahi * 16;
        short8v a = *(const short8v*)(sm + (byte ^ ((row & 7) << 4)));
#pragma unroll
        for (int nt = 0; nt < 5; ++nt) {
            short8v b = WiP[((kk * NT + nt0 + nt) << 6) + lane];
            acc[nt] = __builtin_amdgcn_mfma_f32_16x16x32_bf16(b, a, acc[nt], 0, 0, 0);
        }
    }
    __syncthreads();
#pragma unroll
    for (int nt = 0; nt < 5; ++nt) {
        int byte = row * 640 + (nt0 + nt) * 32 + ahi * 8;
        *(uint2*)(sm + (byte ^ ((row & 7) << 4))) = pack4(acc[nt]);
    }
    __syncthreads();
#pragma unroll
    for (int it = 0; it < 3; ++it) {
        int i = tid + it * 512;
        if (i < 1280) {
            int r = i / CH, c = i % CH;
            int byte = r * 640 + c * 16;
            uint4 v = *(const uint4*)(sm + (byte ^ ((r & 7) << 4)));
            ((uint4*)(inp + (base + r) * HP))[c] = v;
        }
    }
}

// ---------------------------------------------------------------------------
// K2G: AM[a] = fp8( sum_j act(src[a2b[a][j]]) ).
// SRCBF=1: src = inp (bf16, apply relu). SRCBF=0: src = msg (fp8, already relu'd).
// Thread handles 16 hidden elems (one 16B fp8 output chunk).
template<int SRCBF>
__global__ __launch_bounds__(256, 8) void k2_gather(const void* __restrict__ srcv,
                                                    const int* __restrict__ a2b,
                                                    u8* __restrict__ dst) {
    int id = blockIdx.x * 256 + threadIdx.x;
    int atom = id / 20, c = id % 20;
    if (atom >= N_ATOMS) return;
    const int* nb = a2b + atom * MAX_NB;
    float s[16];
#pragma unroll
    for (int q = 0; q < 16; ++q) s[q] = 0.f;
#pragma unroll
    for (int j = 0; j < MAX_NB; ++j) {
        int b = nb[j];
        if (SRCBF) {
            const uint4* rp = (const uint4*)((const u16*)srcv + (long)b * HP);
            uint4 u0 = relu8(rp[2 * c]);
            uint4 u1 = relu8(rp[2 * c + 1]);
            s[0] += us2f(u0.x & 0xffff); s[1] += us2f(u0.x >> 16);
            s[2] += us2f(u0.y & 0xffff); s[3] += us2f(u0.y >> 16);
            s[4] += us2f(u0.z & 0xffff); s[5] += us2f(u0.z >> 16);
            s[6] += us2f(u0.w & 0xffff); s[7] += us2f(u0.w >> 16);
            s[8]  += us2f(u1.x & 0xffff); s[9]  += us2f(u1.x >> 16);
            s[10] += us2f(u1.y & 0xffff); s[11] += us2f(u1.y >> 16);
            s[12] += us2f(u1.z & 0xffff); s[13] += us2f(u1.z >> 16);
            s[14] += us2f(u1.w & 0xffff); s[15] += us2f(u1.w >> 16);
        } else {
            uint4 u = ((const uint4*)((const u8*)srcv + (long)b * 320))[c];
            float v[16];
            f8x16_to_f32(u, v);
#pragma unroll
            for (int q = 0; q < 16; ++q) s[q] += v[q];
        }
    }
    uint4 o;
    o.x = f32x4_to_f8(s[0], s[1], s[2], s[3]);
    o.y = f32x4_to_f8(s[4], s[5], s[6], s[7]);
    o.z = f32x4_to_f8(s[8], s[9], s[10], s[11]);
    o.w = f32x4_to_f8(s[12], s[13], s[14], s[15]);
    ((uint4*)(dst + (long)atom * 320))[c] = o;
}

// ---------------------------------------------------------------------------
// KZF: msg_out(fp8) = relu(inp + (AM[b2a] - act(msgsrc[b2revb])) @ W_h)
// SRCBF=1: msgsrc = inp (bf16, relu applied). SRCBF=0: msgsrc = msg (fp8).
// 32 rows/block, 512 threads; diffs packed bf16 -> LDS -> bf16 MFMA.
template<int SRCBF>
__global__ __launch_bounds__(512, 8) void kzf_update(const u16* __restrict__ inp,
                                                     const u8* __restrict__ AM,
                                                     const void* __restrict__ msgsrcv,
                                                     const int* __restrict__ b2a,
                                                     const int* __restrict__ b2revb,
                                                     const short8v* __restrict__ WhP,
                                                     u8* __restrict__ msgdst) {
    __shared__ __align__(16) char sm[32 * 640];
    const int tid = threadIdx.x;
    const long base = (long)blockIdx.x * 32;
    const int lane = tid & 63, wave = tid >> 6;
    const int rg = wave >> 2;
    const int nt0 = (wave & 3) * 5;
    const int arow0 = lane & 15, ahi = lane >> 4;
    const int row = rg * 16 + arow0;

    // stage: m = AM[b2a[r]] - act(msgsrc[b2revb[r]]), bf16 into LDS (swizzled)
#pragma unroll
    for (int it = 0; it < 2; ++it) {
        int i = tid + it * 512;
        if (i < 640) {
            int r = i / 20, c = i % 20;
            long b = base + r;
            int ia = b2a[b], ir = b2revb[b];
            uint4 ua = ((const uint4*)(AM + (long)ia * 320))[c];
            float av[16];
            f8x16_to_f32(ua, av);
            float mv[16];
            if (SRCBF) {
                const uint4* rp = (const uint4*)((const u16*)msgsrcv + (long)ir * HP);
                uint4 u0 = relu8(rp[2 * c]);
                uint4 u1 = relu8(rp[2 * c + 1]);
                mv[0] = us2f(u0.x & 0xffff); mv[1] = us2f(u0.x >> 16);
                mv[2] = us2f(u0.y & 0xffff); mv[3] = us2f(u0.y >> 16);
                mv[4] = us2f(u0.z & 0xffff); mv[5] = us2f(u0.z >> 16);
                mv[6] = us2f(u0.w & 0xffff); mv[7] = us2f(u0.w >> 16);
                mv[8]  = us2f(u1.x & 0xffff); mv[9]  = us2f(u1.x >> 16);
                mv[10] = us2f(u1.y & 0xffff); mv[11] = us2f(u1.y >> 16);
                mv[12] = us2f(u1.z & 0xffff); mv[13] = us2f(u1.z >> 16);
                mv[14] = us2f(u1.w & 0xffff); mv[15] = us2f(u1.w >> 16);
            } else {
                uint4 um = ((const uint4*)((const u8*)msgsrcv + (long)ir * 320))[c];
                f8x16_to_f32(um, mv);
            }
            uint4 o0, o1;
            o0.x = pack2(av[0] - mv[0], av[1] - mv[1]);
            o0.y = pack2(av[2] - mv[2], av[3] - mv[3]);
            o0.z = pack2(av[4] - mv[4], av[5] - mv[5]);
            o0.w = pack2(av[6] - mv[6], av[7] - mv[7]);
            o1.x = pack2(av[8] - mv[8], av[9] - mv[9]);
            o1.y = pack2(av[10] - mv[10], av[11] - mv[11]);
            o1.z = pack2(av[12] - mv[12], av[13] - mv[13]);
            o1.w = pack2(av[14] - mv[14], av[15] - mv[15]);
            int byte = r * 640 + c * 32;
            int swz = (r & 7) << 4;
            *(uint4*)(sm + (byte ^ swz)) = o0;
            *(uint4*)(sm + ((byte + 16) ^ swz)) = o1;
        }
    }
    __syncthreads();

    float4v acc[5];
#pragma unroll
    for (int nt = 0; nt < 5; ++nt) acc[nt] = {0.f, 0.f, 0.f, 0.f};
    for (int kk = 0; kk < KK_H; ++kk) {
        int byte = row * 640 + kk * 64 + ahi * 16;
        short8v a = *(const short8v*)(sm + (byte ^ ((row & 7) << 4)));
#pragma unroll
        for (int nt = 0; nt < 5; ++nt) {
            short8v b = WhP[((kk * NT + nt0 + nt) << 6) + lane];
            acc[nt] = __builtin_amdgcn_mfma_f32_16x16x32_bf16(b, a, acc[nt], 0, 0, 0);
        }
    }
    __syncthreads();
    // epilogue: relu(acc + inp) -> fp8 into LDS tile [32][320B] (natural banking)
#pragma unroll
    for (int nt = 0; nt < 5; ++nt) {
        uint2 u = *(const uint2*)(inp + (base + row) * HP + (nt0 + nt) * 16 + ahi * 4);
        float v0 = fmaxf(acc[nt][0] + us2f(u.x & 0xffff), 0.f);
        float v1 = fmaxf(acc[nt][1] + us2f(u.x >> 16), 0.f);
        float v2 = fmaxf(acc[nt][2] + us2f(u.y & 0xffff), 0.f);
        float v3 = fmaxf(acc[nt][3] + us2f(u.y >> 16), 0.f);
        *(u32*)(sm + row * 320 + (nt0 + nt) * 16 + ahi * 4) = f32x4_to_f8(v0, v1, v2, v3);
    }
    __syncthreads();
#pragma unroll
    for (int it = 0; it < 2; ++it) {
        int i = tid + it * 512;
        if (i < 640) {
            int r = i / 20, c = i % 20;
            uint4 v = *(const uint4*)(sm + r * 320 + c * 16);
            ((uint4*)(msgdst + (base + r) * 320))[c] = v;
        }
    }
}

// ---------------------------------------------------------------------------
// K4: fused readout + pool. 80 atoms = 4 molecules per block. AM is fp8.
__global__ __launch_bounds__(256) void k4_readout(const float* __restrict__ fa,
                                                  const u8* __restrict__ AM,
                                                  const short8v* __restrict__ WoP,
                                                  const float* __restrict__ bo,
                                                  float* __restrict__ out) {
    __shared__ __align__(16) char sm[80 * 896];
    const int tid = threadIdx.x;
    const long base = (long)blockIdx.x * 80;
    // amsg cols 0..299 (fp8 -> bf16); chunks of 16, c=18 partial (12 elems)
    for (int i = tid; i < 80 * 19; i += 256) {
        int row = i / 19, c = i % 19;
        uint4 u = ((const uint4*)(AM + (base + row) * 320))[c];
        float v[16];
        f8x16_to_f32(u, v);
        uint4 o0, o1;
        o0.x = pack2(v[0], v[1]);  o0.y = pack2(v[2], v[3]);
        o0.z = pack2(v[4], v[5]);  o0.w = pack2(v[6], v[7]);
        o1.x = pack2(v[8], v[9]);  o1.y = pack2(v[10], v[11]);
        o1.z = pack2(v[12], v[13]); o1.w = pack2(v[14], v[15]);
        int byte = row * 896 + c * 32;
        int swz = (row & 7) << 4;
        *(uint4*)(sm + (byte ^ swz)) = o0;
        if (c < 18) {
            *(uint4*)(sm + ((byte + 16) ^ swz)) = o1;
        } else {  // cols 288..299 only: write elems 8..11, skip 12..15
            *(uint2*)(sm + ((byte + 16) ^ swz)) = make_uint2(o1.x, o1.y);
        }
    }
    for (int i = tid; i < 80 * 148; i += 256) {  // f_atoms cols 300..432 + pad
        int row = i / 148, c2 = i % 148;
        float v = (c2 < ATOM_FD) ? fa[(base + row) * ATOM_FD + c2] : 0.f;
        int byte = row * 896 + (HIDDEN + c2) * 2;
        *(u16*)(sm + (byte ^ ((row & 7) << 4))) = f2us(v);
    }
    __syncthreads();

    const int lane = tid & 63, wave = tid >> 6;
    const int nt0 = wave * 5;
    const int arow0 = lane & 15, ahi = lane >> 4;
    float4v acc[5][5];
#pragma unroll
    for (int nt = 0; nt < 5; ++nt)
#pragma unroll
        for (int rg = 0; rg < 5; ++rg) acc[nt][rg] = {0.f, 0.f, 0.f, 0.f};
    for (int kk = 0; kk < KK_O; ++kk) {
        short8v a[5];
#pragma unroll
        for (int rg = 0; rg < 5; ++rg) {
            int row = rg * 16 + arow0;
            int byte = row * 896 + kk * 64 + ahi * 16;
            a[rg] = *(const short8v*)(sm + (byte ^ ((row & 7) << 4)));
        }
#pragma unroll
        for (int nt = 0; nt < 5; ++nt) {
            short8v b = WoP[((kk * NT + nt0 + nt) << 6) + lane];
#pragma unroll
            for (int rg = 0; rg < 5; ++rg)
                acc[nt][rg] = __builtin_amdgcn_mfma_f32_16x16x32_bf16(b, a[rg], acc[nt][rg], 0, 0, 0);
        }
    }
    __syncthreads();
#pragma unroll
    for (int nt = 0; nt < 5; ++nt) {
        int colb = (nt0 + nt) * 16 + ahi * 4;
        float bias[4];
#pragma unroll
        for (int q = 0; q < 4; ++q)
            bias[q] = (colb + q < HIDDEN) ? bo[colb + q] : 0.f;
#pragma unroll
        for (int rg = 0; rg < 5; ++rg) {
            int row = rg * 16 + arow0;
            float4v v;
#pragma unroll
            for (int q = 0; q < 4; ++q) v[q] = fmaxf(acc[nt][rg][q] + bias[q], 0.f);
            int byte = row * 640 + (nt0 + nt) * 32 + ahi * 8;
            *(uint2*)(sm + (byte ^ ((row & 7) << 4))) = pack4(v);
        }
    }
    __syncthreads();
    // pool: 4 molecules x 300 cols, mean over 20 rows each
    for (int idx = tid; idx < 4 * HIDDEN; idx += 256) {
        int m = idx / HIDDEN, col = idx % HIDDEN;
        float s = 0.f;
#pragma unroll
        for (int r = 0; r < APM; ++r) {
            int row = m * APM + r;
            int byte = row * 640 + col * 2;
            s += us2f(*(const u16*)(sm + (byte ^ ((row & 7) << 4))));
        }
        out[((long)blockIdx.x * 4 + m) * HIDDEN + col] = s * (1.f / APM);
    }
}

// ---------------------------------------------------------------------------
extern "C" void kernel_launch(void* const* d_in, const int* in_sizes, int n_in,
                              void* d_out, int out_size, void* d_ws, size_t ws_size,
                              hipStream_t stream) {
    const float* f_atoms = (const float*)d_in[0];
    const float* f_bonds = (const float*)d_in[1];
    const int* a2b = (const int*)d_in[2];
    const int* b2a = (const int*)d_in[3];
    const int* b2revb = (const int*)d_in[4];
    const float* Wi = (const float*)d_in[6];
    const float* Wh = (const float*)d_in[7];
    const float* Wo = (const float*)d_in[8];
    const float* bo = (const float*)d_in[9];
    float* out = (float*)d_out;

    char* ws = (char*)d_ws;
    size_t off = 0;
    auto alloc = [&](size_t bytes) {
        void* p = ws + off;
        off = (off + bytes + 255) & ~(size_t)255;
        return p;
    };
    u16* inp  = (u16*)alloc((size_t)N_BONDS * HP * sizeof(u16));  // 128 MB bf16
    u8* msgA  = (u8*)alloc((size_t)N_BONDS * 320);                //  64 MB fp8
    u8* msgB  = (u8*)alloc((size_t)N_BONDS * 320);                //  64 MB fp8
    u8* AM    = (u8*)alloc((size_t)N_ATOMS * 320);                //  32 MB fp8
    short* WiP = (short*)alloc((size_t)KK_I * NT * 64 * 8 * sizeof(short));
    short* WhP = (short*)alloc((size_t)KK_H * NT * 64 * 8 * sizeof(short));
    short* WoP = (short*)alloc((size_t)KK_O * NT * 64 * 8 * sizeof(short));

    pack_w<<<KK_I * NT, 64, 0, stream>>>(Wi, WiP, BOND_FD, 0);
    pack_w<<<KK_H * NT, 64, 0, stream>>>(Wh, WhP, HIDDEN, 0);
    pack_w<<<KK_O * NT, 64, 0, stream>>>(Wo, WoP, ATOM_FD + HIDDEN, 2);

    k1_input<<<N_BONDS / 32, 512, 0, stream>>>(f_bonds, (const short8v*)WiP, inp);

    const int g2 = (N_ATOMS * 20 + 255) / 256;
    // iter 1: msg0 = relu(inp) applied on the fly (bf16 source)
    k2_gather<1><<<g2, 256, 0, stream>>>(inp, a2b, AM);
    kzf_update<1><<<N_BONDS / 32, 512, 0, stream>>>(inp, AM, inp, b2a, b2revb,
                                                    (const short8v*)WhP, msgA);
    // iter 2 (fp8 sources)
    k2_gather<0><<<g2, 256, 0, stream>>>(msgA, a2b, AM);
    kzf_update<0><<<N_BONDS / 32, 512, 0, stream>>>(inp, AM, msgA, b2a, b2revb,
                                                    (const short8v*)WhP, msgB);
    // readout + pool
    k2_gather<0><<<g2, 256, 0, stream>>>(msgB, a2b, AM);
    k4_readout<<<N_ATOMS / 80, 256, 0, stream>>>(f_atoms, AM,
                                                 (const short8v*)WoP, bo, out);
}

// Round 10
// 578.140 us; speedup vs baseline: 1.6318x; 1.1365x over previous
//
#include <hip/hip_runtime.h>
#include <hip/hip_bf16.h>
#include <hip/hip_fp8.h>

#define N_ATOMS 100000
#define N_BONDS 200000
#define MAX_NB 6
#define HIDDEN 300
#define HP 320               // padded hidden: bf16 row = 640 B; fp8 row = 320 B
#define CH 40
#define ATOM_FD 133
#define BOND_FD 147
#define N_MOLS 5000
#define APM 20

#define NT 20                // 16-col tiles (k4/Wo path)
#define NT32 10              // 32-col tiles (k1/kzf path)
#define KKI32 10             // K=160 >= 147 in 16-steps
#define KKH32 20             // K=320 >= 300 in 16-steps
#define KK_O 14              // K=448 >= 433 in 32-steps (k4)

using bf16 = __hip_bfloat16;
typedef __attribute__((ext_vector_type(8))) short short8v;
typedef __attribute__((ext_vector_type(4))) float float4v;
typedef __attribute__((ext_vector_type(16))) float float16v;
typedef unsigned int u32;
typedef unsigned short u16;
typedef unsigned char u8;

__device__ __forceinline__ float us2f(u16 u) {
    union { u32 i; float f; } v; v.i = ((u32)u) << 16; return v.f;
}
__device__ __forceinline__ u16 f2us(float f) {
    bf16 h = __float2bfloat16(f);
    return *(u16*)&h;
}
__device__ __forceinline__ u32 pack2(float a, float b) {
    return (u32)f2us(a) | ((u32)f2us(b) << 16);
}
__device__ __forceinline__ uint2 pack4(const float4v& a) {
    uint2 o; o.x = pack2(a[0], a[1]); o.y = pack2(a[2], a[3]); return o;
}
__device__ __forceinline__ u32 relu2(u32 u) {
    u32 r = (u & 0x80000000u) ? (u & 0x0000ffffu) : u;
    r = (r & 0x8000u) ? (r & 0xffff0000u) : r;
    return r;
}
__device__ __forceinline__ uint4 relu8(uint4 u) {
    u.x = relu2(u.x); u.y = relu2(u.y); u.z = relu2(u.z); u.w = relu2(u.w);
    return u;
}

// ---- fp8 e4m3 (OCP on gfx950) conversion helpers -------------------------
#if defined(__has_builtin)
#if __has_builtin(__builtin_amdgcn_cvt_f32_fp8) && __has_builtin(__builtin_amdgcn_cvt_pk_fp8_f32)
#define HW_FP8 1
#endif
#endif

__device__ __forceinline__ void f8x4_to_f32(u32 p, float* o) {
#ifdef HW_FP8
    o[0] = __builtin_amdgcn_cvt_f32_fp8(p, 0);
    o[1] = __builtin_amdgcn_cvt_f32_fp8(p, 1);
    o[2] = __builtin_amdgcn_cvt_f32_fp8(p, 2);
    o[3] = __builtin_amdgcn_cvt_f32_fp8(p, 3);
#else
#pragma unroll
    for (int i = 0; i < 4; ++i) {
        __hip_fp8_e4m3 h; h.__x = (u8)(p >> (8 * i));
        o[i] = (float)h;
    }
#endif
}
__device__ __forceinline__ u32 f32x4_to_f8(float a, float b, float c, float d) {
#ifdef HW_FP8
    u32 r = __builtin_amdgcn_cvt_pk_fp8_f32(a, b, 0u, false);
    r = __builtin_amdgcn_cvt_pk_fp8_f32(c, d, r, true);
    return r;
#else
    __hip_fp8_e4m3 ha(a), hb(b), hc(c), hd(d);
    return (u32)ha.__x | ((u32)hb.__x << 8) | ((u32)hc.__x << 16) | ((u32)hd.__x << 24);
#endif
}
__device__ __forceinline__ void f8x16_to_f32(uint4 u, float* o) {
    f8x4_to_f32(u.x, o); f8x4_to_f32(u.y, o + 4);
    f8x4_to_f32(u.z, o + 8); f8x4_to_f32(u.w, o + 12);
}

// ---------------------------------------------------------------------------
// pack_w: W [Ksrc x 300] fp32 -> bf16 MFMA-A fragments, 16-col tiles (Wo path)
// mode==2 (W_o): K layout is [amsg(0..299) | f_atoms(300..432)].
__global__ __launch_bounds__(64) void pack_w(const float* __restrict__ src,
                                             short* __restrict__ dst,
                                             int Ksrc, int mode) {
    int kk = blockIdx.x / NT, nt = blockIdx.x % NT;
    int lane = threadIdx.x;
    int col = nt * 16 + (lane & 15);
#pragma unroll
    for (int j = 0; j < 8; ++j) {
        int k = kk * 32 + (lane >> 4) * 8 + j;
        float v = 0.f;
        if (k < Ksrc && col < HIDDEN) {
            int krow = k;
            if (mode == 2) krow = (k < HIDDEN) ? (ATOM_FD + k) : (k - HIDDEN);
            v = src[krow * HIDDEN + col];
        }
        dst[(((kk * NT + nt) << 6) + lane) * 8 + j] = (short)f2us(v);
    }
}

// pack_w32: W [Ksrc x 300] fp32 -> 32x32x16 MFMA-A fragments [kk16][NT32][64][8]
// lane holds W[kk*16 + (l>>5)*8 + j][nt*32 + (l&31)].
__global__ __launch_bounds__(64) void pack_w32(const float* __restrict__ src,
                                               short* __restrict__ dst,
                                               int Ksrc) {
    int kk = blockIdx.x / NT32, nt = blockIdx.x % NT32;
    int lane = threadIdx.x;
    int col = nt * 32 + (lane & 31);
#pragma unroll
    for (int j = 0; j < 8; ++j) {
        int k = kk * 16 + (lane >> 5) * 8 + j;
        float v = 0.f;
        if (k < Ksrc && col < HIDDEN) v = src[k * HIDDEN + col];
        dst[(((kk * NT32 + nt) << 6) + lane) * 8 + j] = (short)f2us(v);
    }
}

// ---------------------------------------------------------------------------
// K1: inp = f_bonds @ W_i (bf16 out). 32 rows/block, 640 threads = 10 waves,
// one 32-col tile per wave, 32x32x16 MFMA (weights read once per block).
__global__ __launch_bounds__(640, 8) void k1_input(const float* __restrict__ fb,
                                                   const short8v* __restrict__ WiP,
                                                   u16* __restrict__ inp) {
    __shared__ __align__(16) char sm[32 * 320];    // staged fb bf16 (160 cols)
    __shared__ __align__(16) char smo[32 * 640];   // output bf16 tile
    const int tid = threadIdx.x;
    const long base = (long)blockIdx.x * 32;
#pragma unroll
    for (int it = 0; it < 8; ++it) {
        int i = tid + it * 640;
        int row = i / 160, c = i % 160;
        float v = (c < BOND_FD) ? fb[(base + row) * BOND_FD + c] : 0.f;
        int byte = row * 320 + c * 2;
        *(u16*)(sm + (byte ^ ((row & 7) << 4))) = f2us(v);
    }
    __syncthreads();

    const int lane = tid & 63, wave = tid >> 6;   // wave = nt32 tile 0..9
    const int row = lane & 31, hi = lane >> 5;
    float16v acc;
#pragma unroll
    for (int q = 0; q < 16; ++q) acc[q] = 0.f;
    for (int kk = 0; kk < KKI32; ++kk) {
        int byte = row * 320 + kk * 32 + hi * 16;
        short8v a = *(const short8v*)(sm + (byte ^ ((row & 7) << 4)));
        short8v w = WiP[((kk * NT32 + wave) << 6) + lane];
        acc = __builtin_amdgcn_mfma_f32_32x32x16_bf16(w, a, acc, 0, 0, 0);
    }
    // epilogue: lane holds bond-row=lane&31, hidden cols (reg&3)+8*(reg>>2)+4*hi
#pragma unroll
    for (int q = 0; q < 4; ++q) {
        float4v v;
#pragma unroll
        for (int d = 0; d < 4; ++d) v[d] = acc[4 * q + d];
        int byte = row * 640 + wave * 64 + q * 16 + hi * 8;
        *(uint2*)(smo + (byte ^ ((row & 7) << 4))) = pack4(v);
    }
    __syncthreads();
#pragma unroll
    for (int it = 0; it < 2; ++it) {
        int i = tid + it * 640;
        if (i < 1280) {
            int r = i / CH, c = i % CH;
            int byte = r * 640 + c * 16;
            uint4 v = *(const uint4*)(smo + (byte ^ ((r & 7) << 4)));
            ((uint4*)(inp + (base + r) * HP))[c] = v;
        }
    }
}

// ---------------------------------------------------------------------------
// K2G: AM[a] = fp8( sum_j act(src[a2b[a][j]]) ).  (unchanged)
template<int SRCBF>
__global__ __launch_bounds__(256, 8) void k2_gather(const void* __restrict__ srcv,
                                                    const int* __restrict__ a2b,
                                                    u8* __restrict__ dst) {
    int id = blockIdx.x * 256 + threadIdx.x;
    int atom = id / 20, c = id % 20;
    if (atom >= N_ATOMS) return;
    const int* nb = a2b + atom * MAX_NB;
    float s[16];
#pragma unroll
    for (int q = 0; q < 16; ++q) s[q] = 0.f;
#pragma unroll
    for (int j = 0; j < MAX_NB; ++j) {
        int b = nb[j];
        if (SRCBF) {
            const uint4* rp = (const uint4*)((const u16*)srcv + (long)b * HP);
            uint4 u0 = relu8(rp[2 * c]);
            uint4 u1 = relu8(rp[2 * c + 1]);
            s[0] += us2f(u0.x & 0xffff); s[1] += us2f(u0.x >> 16);
            s[2] += us2f(u0.y & 0xffff); s[3] += us2f(u0.y >> 16);
            s[4] += us2f(u0.z & 0xffff); s[5] += us2f(u0.z >> 16);
            s[6] += us2f(u0.w & 0xffff); s[7] += us2f(u0.w >> 16);
            s[8]  += us2f(u1.x & 0xffff); s[9]  += us2f(u1.x >> 16);
            s[10] += us2f(u1.y & 0xffff); s[11] += us2f(u1.y >> 16);
            s[12] += us2f(u1.z & 0xffff); s[13] += us2f(u1.z >> 16);
            s[14] += us2f(u1.w & 0xffff); s[15] += us2f(u1.w >> 16);
        } else {
            uint4 u = ((const uint4*)((const u8*)srcv + (long)b * 320))[c];
            float v[16];
            f8x16_to_f32(u, v);
#pragma unroll
            for (int q = 0; q < 16; ++q) s[q] += v[q];
        }
    }
    uint4 o;
    o.x = f32x4_to_f8(s[0], s[1], s[2], s[3]);
    o.y = f32x4_to_f8(s[4], s[5], s[6], s[7]);
    o.z = f32x4_to_f8(s[8], s[9], s[10], s[11]);
    o.w = f32x4_to_f8(s[12], s[13], s[14], s[15]);
    ((uint4*)(dst + (long)atom * 320))[c] = o;
}

// ---------------------------------------------------------------------------
// KZF: msg_out(fp8) = relu(inp + (AM[b2a] - act(msgsrc[b2revb])) @ W_h)
// 32 rows/block, 640 threads = 10 waves, one 32-col tile/wave, 32x32x16 MFMA.
// Weight fragments read exactly once per block (no wave duplication).
template<int SRCBF>
__global__ __launch_bounds__(640, 8) void kzf_update(const u16* __restrict__ inp,
                                                     const u8* __restrict__ AM,
                                                     const void* __restrict__ msgsrcv,
                                                     const int* __restrict__ b2a,
                                                     const int* __restrict__ b2revb,
                                                     const short8v* __restrict__ WhP,
                                                     u8* __restrict__ msgdst) {
    __shared__ __align__(16) char sm[32 * 640];    // bf16 m tile (swizzled)
    __shared__ __align__(16) char sm8[32 * 336];   // fp8 out tile (padded row)
    const int tid = threadIdx.x;
    const long base = (long)blockIdx.x * 32;

    // stage: exactly one 16-elem chunk per thread (32 rows x 20 chunks = 640)
    {
        int r = tid / 20, c = tid % 20;
        long b = base + r;
        int ia = b2a[b], ir = b2revb[b];
        uint4 ua = ((const uint4*)(AM + (long)ia * 320))[c];
        float av[16];
        f8x16_to_f32(ua, av);
        float mv[16];
        if (SRCBF) {
            const uint4* rp = (const uint4*)((const u16*)msgsrcv + (long)ir * HP);
            uint4 u0 = relu8(rp[2 * c]);
            uint4 u1 = relu8(rp[2 * c + 1]);
            mv[0] = us2f(u0.x & 0xffff); mv[1] = us2f(u0.x >> 16);
            mv[2] = us2f(u0.y & 0xffff); mv[3] = us2f(u0.y >> 16);
            mv[4] = us2f(u0.z & 0xffff); mv[5] = us2f(u0.z >> 16);
            mv[6] = us2f(u0.w & 0xffff); mv[7] = us2f(u0.w >> 16);
            mv[8]  = us2f(u1.x & 0xffff); mv[9]  = us2f(u1.x >> 16);
            mv[10] = us2f(u1.y & 0xffff); mv[11] = us2f(u1.y >> 16);
            mv[12] = us2f(u1.z & 0xffff); mv[13] = us2f(u1.z >> 16);
            mv[14] = us2f(u1.w & 0xffff); mv[15] = us2f(u1.w >> 16);
        } else {
            uint4 um = ((const uint4*)((const u8*)msgsrcv + (long)ir * 320))[c];
            f8x16_to_f32(um, mv);
        }
        uint4 o0, o1;
        o0.x = pack2(av[0] - mv[0], av[1] - mv[1]);
        o0.y = pack2(av[2] - mv[2], av[3] - mv[3]);
        o0.z = pack2(av[4] - mv[4], av[5] - mv[5]);
        o0.w = pack2(av[6] - mv[6], av[7] - mv[7]);
        o1.x = pack2(av[8] - mv[8], av[9] - mv[9]);
        o1.y = pack2(av[10] - mv[10], av[11] - mv[11]);
        o1.z = pack2(av[12] - mv[12], av[13] - mv[13]);
        o1.w = pack2(av[14] - mv[14], av[15] - mv[15]);
        int byte = r * 640 + c * 32;
        int swz = (r & 7) << 4;
        *(uint4*)(sm + (byte ^ swz)) = o0;
        *(uint4*)(sm + ((byte + 16) ^ swz)) = o1;
    }
    __syncthreads();

    const int lane = tid & 63, wave = tid >> 6;   // wave = nt32 tile 0..9
    const int row = lane & 31, hi = lane >> 5;
    float16v acc;
#pragma unroll
    for (int q = 0; q < 16; ++q) acc[q] = 0.f;
    for (int kk = 0; kk < KKH32; ++kk) {
        int byte = row * 640 + kk * 32 + hi * 16;
        short8v a = *(const short8v*)(sm + (byte ^ ((row & 7) << 4)));
        short8v w = WhP[((kk * NT32 + wave) << 6) + lane];
        acc = __builtin_amdgcn_mfma_f32_32x32x16_bf16(w, a, acc, 0, 0, 0);
    }
    // epilogue: relu(acc + inp) -> fp8 tile (336B-padded rows, bank-spread)
#pragma unroll
    for (int q = 0; q < 4; ++q) {
        int colb = wave * 32 + q * 8 + hi * 4;
        uint2 u = *(const uint2*)(inp + (base + row) * HP + colb);
        float v0 = fmaxf(acc[4 * q + 0] + us2f(u.x & 0xffff), 0.f);
        float v1 = fmaxf(acc[4 * q + 1] + us2f(u.x >> 16), 0.f);
        float v2 = fmaxf(acc[4 * q + 2] + us2f(u.y & 0xffff), 0.f);
        float v3 = fmaxf(acc[4 * q + 3] + us2f(u.y >> 16), 0.f);
        *(u32*)(sm8 + row * 336 + colb) = f32x4_to_f8(v0, v1, v2, v3);
    }
    __syncthreads();
    {
        int r = tid / 20, c = tid % 20;
        uint4 v = *(const uint4*)(sm8 + r * 336 + c * 16);
        ((uint4*)(msgdst + (base + r) * 320))[c] = v;
    }
}

// ---------------------------------------------------------------------------
// K4: fused readout + pool. 80 atoms = 4 molecules per block. AM is fp8.
__global__ __launch_bounds__(256) void k4_readout(const float* __restrict__ fa,
                                                  const u8* __restrict__ AM,
                                                  const short8v* __restrict__ WoP,
                                                  const float* __restrict__ bo,
                                                  float* __restrict__ out) {
    __shared__ __align__(16) char sm[80 * 896];
    const int tid = threadIdx.x;
    const long base = (long)blockIdx.x * 80;
    // amsg cols 0..299 (fp8 -> bf16); chunks of 16, c=18 partial (12 elems)
    for (int i = tid; i < 80 * 19; i += 256) {
        int row = i / 19, c = i % 19;
        uint4 u = ((const uint4*)(AM + (base + row) * 320))[c];
        float v[16];
        f8x16_to_f32(u, v);
        uint4 o0, o1;
        o0.x = pack2(v[0], v[1]);  o0.y = pack2(v[2], v[3]);
        o0.z = pack2(v[4], v[5]);  o0.w = pack2(v[6], v[7]);
        o1.x = pack2(v[8], v[9]);  o1.y = pack2(v[10], v[11]);
        o1.z = pack2(v[12], v[13]); o1.w = pack2(v[14], v[15]);
        int byte = row * 896 + c * 32;
        int swz = (row & 7) << 4;
        *(uint4*)(sm + (byte ^ swz)) = o0;
        if (c < 18) {
            *(uint4*)(sm + ((byte + 16) ^ swz)) = o1;
        } else {  // cols 288..299 only: write elems 8..11, skip 12..15
            *(uint2*)(sm + ((byte + 16) ^ swz)) = make_uint2(o1.x, o1.y);
        }
    }
    for (int i = tid; i < 80 * 148; i += 256) {  // f_atoms cols 300..432 + pad
        int row = i / 148, c2 = i % 148;
        float v = (c2 < ATOM_FD) ? fa[(base + row) * ATOM_FD + c2] : 0.f;
        int byte = row * 896 + (HIDDEN + c2) * 2;
        *(u16*)(sm + (byte ^ ((row & 7) << 4))) = f2us(v);
    }
    __syncthreads();

    const int lane = tid & 63, wave = tid >> 6;
    const int nt0 = wave * 5;
    const int arow0 = lane & 15, ahi = lane >> 4;
    float4v acc[5][5];
#pragma unroll
    for (int nt = 0; nt < 5; ++nt)
#pragma unroll
        for (int rg = 0; rg < 5; ++rg) acc[nt][rg] = {0.f, 0.f, 0.f, 0.f};
    for (int kk = 0; kk < KK_O; ++kk) {
        short8v a[5];
#pragma unroll
        for (int rg = 0; rg < 5; ++rg) {
            int row = rg * 16 + arow0;
            int byte = row * 896 + kk * 64 + ahi * 16;
            a[rg] = *(const short8v*)(sm + (byte ^ ((row & 7) << 4)));
        }
#pragma unroll
        for (int nt = 0; nt < 5; ++nt) {
            short8v b = WoP[((kk * NT + nt0 + nt) << 6) + lane];
#pragma unroll
            for (int rg = 0; rg < 5; ++rg)
                acc[nt][rg] = __builtin_amdgcn_mfma_f32_16x16x32_bf16(b, a[rg], acc[nt][rg], 0, 0, 0);
        }
    }
    __syncthreads();
#pragma unroll
    for (int nt = 0; nt < 5; ++nt) {
        int colb = (nt0 + nt) * 16 + ahi * 4;
        float bias[4];
#pragma unroll
        for (int q = 0; q < 4; ++q)
            bias[q] = (colb + q < HIDDEN) ? bo[colb + q] : 0.f;
#pragma unroll
        for (int rg = 0; rg < 5; ++rg) {
            int row = rg * 16 + arow0;
            float4v v;
#pragma unroll
            for (int q = 0; q < 4; ++q) v[q] = fmaxf(acc[nt][rg][q] + bias[q], 0.f);
            int byte = row * 640 + (nt0 + nt) * 32 + ahi * 8;
            *(uint2*)(sm + (byte ^ ((row & 7) << 4))) = pack4(v);
        }
    }
    __syncthreads();
    // pool: 4 molecules x 300 cols, mean over 20 rows each
    for (int idx = tid; idx < 4 * HIDDEN; idx += 256) {
        int m = idx / HIDDEN, col = idx % HIDDEN;
        float s = 0.f;
#pragma unroll
        for (int r = 0; r < APM; ++r) {
            int row = m * APM + r;
            int byte = row * 640 + col * 2;
            s += us2f(*(const u16*)(sm + (byte ^ ((row & 7) << 4))));
        }
        out[((long)blockIdx.x * 4 + m) * HIDDEN + col] = s * (1.f / APM);
    }
}

// ---------------------------------------------------------------------------
extern "C" void kernel_launch(void* const* d_in, const int* in_sizes, int n_in,
                              void* d_out, int out_size, void* d_ws, size_t ws_size,
                              hipStream_t stream) {
    const float* f_atoms = (const float*)d_in[0];
    const float* f_bonds = (const float*)d_in[1];
    const int* a2b = (const int*)d_in[2];
    const int* b2a = (const int*)d_in[3];
    const int* b2revb = (const int*)d_in[4];
    const float* Wi = (const float*)d_in[6];
    const float* Wh = (const float*)d_in[7];
    const float* Wo = (const float*)d_in[8];
    const float* bo = (const float*)d_in[9];
    float* out = (float*)d_out;

    char* ws = (char*)d_ws;
    size_t off = 0;
    auto alloc = [&](size_t bytes) {
        void* p = ws + off;
        off = (off + bytes + 255) & ~(size_t)255;
        return p;
    };
    u16* inp  = (u16*)alloc((size_t)N_BONDS * HP * sizeof(u16));  // 128 MB bf16
    u8* msgA  = (u8*)alloc((size_t)N_BONDS * 320);                //  64 MB fp8
    u8* msgB  = (u8*)alloc((size_t)N_BONDS * 320);                //  64 MB fp8
    u8* AM    = (u8*)alloc((size_t)N_ATOMS * 320);                //  32 MB fp8
    short* WiP32 = (short*)alloc((size_t)KKI32 * NT32 * 64 * 8 * sizeof(short));
    short* WhP32 = (short*)alloc((size_t)KKH32 * NT32 * 64 * 8 * sizeof(short));
    short* WoP   = (short*)alloc((size_t)KK_O * NT * 64 * 8 * sizeof(short));

    pack_w32<<<KKI32 * NT32, 64, 0, stream>>>(Wi, WiP32, BOND_FD);
    pack_w32<<<KKH32 * NT32, 64, 0, stream>>>(Wh, WhP32, HIDDEN);
    pack_w<<<KK_O * NT, 64, 0, stream>>>(Wo, WoP, ATOM_FD + HIDDEN, 2);

    k1_input<<<N_BONDS / 32, 640, 0, stream>>>(f_bonds, (const short8v*)WiP32, inp);

    const int g2 = (N_ATOMS * 20 + 255) / 256;
    // iter 1: msg0 = relu(inp) applied on the fly (bf16 source)
    k2_gather<1><<<g2, 256, 0, stream>>>(inp, a2b, AM);
    kzf_update<1><<<N_BONDS / 32, 640, 0, stream>>>(inp, AM, inp, b2a, b2revb,
                                                    (const short8v*)WhP32, msgA);
    // iter 2 (fp8 sources)
    k2_gather<0><<<g2, 256, 0, stream>>>(msgA, a2b, AM);
    kzf_update<0><<<N_BONDS / 32, 640, 0, stream>>>(inp, AM, msgA, b2a, b2revb,
                                                    (const short8v*)WhP32, msgB);
    // readout + pool
    k2_gather<0><<<g2, 256, 0, stream>>>(msgB, a2b, AM);
    k4_readout<<<N_ATOMS / 80, 256, 0, stream>>>(f_atoms, AM,
                                                 (const short8v*)WoP, bo, out);
}

// Round 11
// 549.880 us; speedup vs baseline: 1.7157x; 1.0514x over previous
//
#include <hip/hip_runtime.h>
#include <hip/hip_bf16.h>
#include <hip/hip_fp8.h>

#define N_ATOMS 100000
#define N_BONDS 200000
#define MAX_NB 6
#define HIDDEN 300
#define HP 320               // padded hidden: bf16 row = 640 B; fp8 row = 320 B
#define CH 40
#define ATOM_FD 133
#define BOND_FD 147
#define N_MOLS 5000
#define APM 20

#define NT32 10              // 32-col tiles
#define KKI32 10             // K=160 >= 147 in 16-steps
#define KKH32 20             // K=320 >= 300 in 16-steps
#define KKO32 28             // K=448 >= 433 in 16-steps

using bf16 = __hip_bfloat16;
typedef __attribute__((ext_vector_type(8))) short short8v;
typedef __attribute__((ext_vector_type(4))) float float4v;
typedef __attribute__((ext_vector_type(16))) float float16v;
typedef unsigned int u32;
typedef unsigned short u16;
typedef unsigned char u8;

__device__ __forceinline__ float us2f(u16 u) {
    union { u32 i; float f; } v; v.i = ((u32)u) << 16; return v.f;
}
__device__ __forceinline__ u16 f2us(float f) {
    bf16 h = __float2bfloat16(f);
    return *(u16*)&h;
}
__device__ __forceinline__ u32 pack2(float a, float b) {
    return (u32)f2us(a) | ((u32)f2us(b) << 16);
}
__device__ __forceinline__ uint2 pack4(const float4v& a) {
    uint2 o; o.x = pack2(a[0], a[1]); o.y = pack2(a[2], a[3]); return o;
}
__device__ __forceinline__ u32 relu2(u32 u) {
    u32 r = (u & 0x80000000u) ? (u & 0x0000ffffu) : u;
    r = (r & 0x8000u) ? (r & 0xffff0000u) : r;
    return r;
}
__device__ __forceinline__ uint4 relu8(uint4 u) {
    u.x = relu2(u.x); u.y = relu2(u.y); u.z = relu2(u.z); u.w = relu2(u.w);
    return u;
}

// ---- fp8 e4m3 (OCP on gfx950) conversion helpers -------------------------
#if defined(__has_builtin)
#if __has_builtin(__builtin_amdgcn_cvt_f32_fp8) && __has_builtin(__builtin_amdgcn_cvt_pk_fp8_f32)
#define HW_FP8 1
#endif
#endif

__device__ __forceinline__ void f8x4_to_f32(u32 p, float* o) {
#ifdef HW_FP8
    o[0] = __builtin_amdgcn_cvt_f32_fp8(p, 0);
    o[1] = __builtin_amdgcn_cvt_f32_fp8(p, 1);
    o[2] = __builtin_amdgcn_cvt_f32_fp8(p, 2);
    o[3] = __builtin_amdgcn_cvt_f32_fp8(p, 3);
#else
#pragma unroll
    for (int i = 0; i < 4; ++i) {
        __hip_fp8_e4m3 h; h.__x = (u8)(p >> (8 * i));
        o[i] = (float)h;
    }
#endif
}
__device__ __forceinline__ u32 f32x4_to_f8(float a, float b, float c, float d) {
#ifdef HW_FP8
    u32 r = __builtin_amdgcn_cvt_pk_fp8_f32(a, b, 0u, false);
    r = __builtin_amdgcn_cvt_pk_fp8_f32(c, d, r, true);
    return r;
#else
    __hip_fp8_e4m3 ha(a), hb(b), hc(c), hd(d);
    return (u32)ha.__x | ((u32)hb.__x << 8) | ((u32)hc.__x << 16) | ((u32)hd.__x << 24);
#endif
}
__device__ __forceinline__ void f8x16_to_f32(uint4 u, float* o) {
    f8x4_to_f32(u.x, o); f8x4_to_f32(u.y, o + 4);
    f8x4_to_f32(u.z, o + 8); f8x4_to_f32(u.w, o + 12);
}

// ---------------------------------------------------------------------------
// pack_w32: W [Ksrc x 300] fp32 -> 32x32x16 MFMA fragments [kk16][NT32][64][8]
// lane holds W[kk*16 + (l>>5)*8 + j][nt*32 + (l&31)].
// mode==2 (W_o): K layout is [amsg(0..299) | f_atoms(300..432)].
__global__ __launch_bounds__(64) void pack_w32(const float* __restrict__ src,
                                               short* __restrict__ dst,
                                               int Ksrc, int mode) {
    int kk = blockIdx.x / NT32, nt = blockIdx.x % NT32;
    int lane = threadIdx.x;
    int col = nt * 32 + (lane & 31);
#pragma unroll
    for (int j = 0; j < 8; ++j) {
        int k = kk * 16 + (lane >> 5) * 8 + j;
        float v = 0.f;
        if (k < Ksrc && col < HIDDEN) {
            int krow = k;
            if (mode == 2) krow = (k < HIDDEN) ? (ATOM_FD + k) : (k - HIDDEN);
            v = src[krow * HIDDEN + col];
        }
        dst[(((kk * NT32 + nt) << 6) + lane) * 8 + j] = (short)f2us(v);
    }
}

// ---------------------------------------------------------------------------
// K1: inp = f_bonds @ W_i (bf16 out). 32 rows/block, 640 threads = 10 waves,
// one 32-col tile per wave, 32x32x16 MFMA (weights read once per block).
__global__ __launch_bounds__(640, 8) void k1_input(const float* __restrict__ fb,
                                                   const short8v* __restrict__ WiP,
                                                   u16* __restrict__ inp) {
    __shared__ __align__(16) char sm[32 * 320];    // staged fb bf16 (160 cols)
    __shared__ __align__(16) char smo[32 * 640];   // output bf16 tile
    const int tid = threadIdx.x;
    const long base = (long)blockIdx.x * 32;
#pragma unroll
    for (int it = 0; it < 8; ++it) {
        int i = tid + it * 640;
        int row = i / 160, c = i % 160;
        float v = (c < BOND_FD) ? fb[(base + row) * BOND_FD + c] : 0.f;
        int byte = row * 320 + c * 2;
        *(u16*)(sm + (byte ^ ((row & 7) << 4))) = f2us(v);
    }
    __syncthreads();

    const int lane = tid & 63, wave = tid >> 6;   // wave = nt32 tile 0..9
    const int row = lane & 31, hi = lane >> 5;
    float16v acc;
#pragma unroll
    for (int q = 0; q < 16; ++q) acc[q] = 0.f;
    for (int kk = 0; kk < KKI32; ++kk) {
        int byte = row * 320 + kk * 32 + hi * 16;
        short8v a = *(const short8v*)(sm + (byte ^ ((row & 7) << 4)));
        short8v w = WiP[((kk * NT32 + wave) << 6) + lane];
        acc = __builtin_amdgcn_mfma_f32_32x32x16_bf16(w, a, acc, 0, 0, 0);
    }
    // epilogue: lane holds bond-row=lane&31, hidden cols wave*32+q*8+hi*4 (+d)
#pragma unroll
    for (int q = 0; q < 4; ++q) {
        float4v v;
#pragma unroll
        for (int d = 0; d < 4; ++d) v[d] = acc[4 * q + d];
        int byte = row * 640 + wave * 64 + q * 16 + hi * 8;
        *(uint2*)(smo + (byte ^ ((row & 7) << 4))) = pack4(v);
    }
    __syncthreads();
#pragma unroll
    for (int it = 0; it < 2; ++it) {
        int i = tid + it * 640;
        if (i < 1280) {
            int r = i / CH, c = i % CH;
            int byte = r * 640 + c * 16;
            uint4 v = *(const uint4*)(smo + (byte ^ ((r & 7) << 4)));
            ((uint4*)(inp + (base + r) * HP))[c] = v;
        }
    }
}

// ---------------------------------------------------------------------------
// K2G: AM[a] = fp8( sum_j act(src[a2b[a][j]]) ).  (unchanged)
template<int SRCBF>
__global__ __launch_bounds__(256, 8) void k2_gather(const void* __restrict__ srcv,
                                                    const int* __restrict__ a2b,
                                                    u8* __restrict__ dst) {
    int id = blockIdx.x * 256 + threadIdx.x;
    int atom = id / 20, c = id % 20;
    if (atom >= N_ATOMS) return;
    const int* nb = a2b + atom * MAX_NB;
    float s[16];
#pragma unroll
    for (int q = 0; q < 16; ++q) s[q] = 0.f;
#pragma unroll
    for (int j = 0; j < MAX_NB; ++j) {
        int b = nb[j];
        if (SRCBF) {
            const uint4* rp = (const uint4*)((const u16*)srcv + (long)b * HP);
            uint4 u0 = relu8(rp[2 * c]);
            uint4 u1 = relu8(rp[2 * c + 1]);
            s[0] += us2f(u0.x & 0xffff); s[1] += us2f(u0.x >> 16);
            s[2] += us2f(u0.y & 0xffff); s[3] += us2f(u0.y >> 16);
            s[4] += us2f(u0.z & 0xffff); s[5] += us2f(u0.z >> 16);
            s[6] += us2f(u0.w & 0xffff); s[7] += us2f(u0.w >> 16);
            s[8]  += us2f(u1.x & 0xffff); s[9]  += us2f(u1.x >> 16);
            s[10] += us2f(u1.y & 0xffff); s[11] += us2f(u1.y >> 16);
            s[12] += us2f(u1.z & 0xffff); s[13] += us2f(u1.z >> 16);
            s[14] += us2f(u1.w & 0xffff); s[15] += us2f(u1.w >> 16);
        } else {
            uint4 u = ((const uint4*)((const u8*)srcv + (long)b * 320))[c];
            float v[16];
            f8x16_to_f32(u, v);
#pragma unroll
            for (int q = 0; q < 16; ++q) s[q] += v[q];
        }
    }
    uint4 o;
    o.x = f32x4_to_f8(s[0], s[1], s[2], s[3]);
    o.y = f32x4_to_f8(s[4], s[5], s[6], s[7]);
    o.z = f32x4_to_f8(s[8], s[9], s[10], s[11]);
    o.w = f32x4_to_f8(s[12], s[13], s[14], s[15]);
    ((uint4*)(dst + (long)atom * 320))[c] = o;
}

// ---------------------------------------------------------------------------
// KZF: msg_out(fp8) = relu(inp + (AM[b2a] - act(msgsrc[b2revb])) @ W_h)
// 32 rows/block, 640 threads = 10 waves, one 32-col tile/wave, 32x32x16 MFMA.
template<int SRCBF>
__global__ __launch_bounds__(640, 8) void kzf_update(const u16* __restrict__ inp,
                                                     const u8* __restrict__ AM,
                                                     const void* __restrict__ msgsrcv,
                                                     const int* __restrict__ b2a,
                                                     const int* __restrict__ b2revb,
                                                     const short8v* __restrict__ WhP,
                                                     u8* __restrict__ msgdst) {
    __shared__ __align__(16) char sm[32 * 640];    // bf16 m tile (swizzled)
    __shared__ __align__(16) char sm8[32 * 336];   // fp8 out tile (padded row)
    const int tid = threadIdx.x;
    const long base = (long)blockIdx.x * 32;

    // stage: exactly one 16-elem chunk per thread (32 rows x 20 chunks = 640)
    {
        int r = tid / 20, c = tid % 20;
        long b = base + r;
        int ia = b2a[b], ir = b2revb[b];
        uint4 ua = ((const uint4*)(AM + (long)ia * 320))[c];
        float av[16];
        f8x16_to_f32(ua, av);
        float mv[16];
        if (SRCBF) {
            const uint4* rp = (const uint4*)((const u16*)msgsrcv + (long)ir * HP);
            uint4 u0 = relu8(rp[2 * c]);
            uint4 u1 = relu8(rp[2 * c + 1]);
            mv[0] = us2f(u0.x & 0xffff); mv[1] = us2f(u0.x >> 16);
            mv[2] = us2f(u0.y & 0xffff); mv[3] = us2f(u0.y >> 16);
            mv[4] = us2f(u0.z & 0xffff); mv[5] = us2f(u0.z >> 16);
            mv[6] = us2f(u0.w & 0xffff); mv[7] = us2f(u0.w >> 16);
            mv[8]  = us2f(u1.x & 0xffff); mv[9]  = us2f(u1.x >> 16);
            mv[10] = us2f(u1.y & 0xffff); mv[11] = us2f(u1.y >> 16);
            mv[12] = us2f(u1.z & 0xffff); mv[13] = us2f(u1.z >> 16);
            mv[14] = us2f(u1.w & 0xffff); mv[15] = us2f(u1.w >> 16);
        } else {
            uint4 um = ((const uint4*)((const u8*)msgsrcv + (long)ir * 320))[c];
            f8x16_to_f32(um, mv);
        }
        uint4 o0, o1;
        o0.x = pack2(av[0] - mv[0], av[1] - mv[1]);
        o0.y = pack2(av[2] - mv[2], av[3] - mv[3]);
        o0.z = pack2(av[4] - mv[4], av[5] - mv[5]);
        o0.w = pack2(av[6] - mv[6], av[7] - mv[7]);
        o1.x = pack2(av[8] - mv[8], av[9] - mv[9]);
        o1.y = pack2(av[10] - mv[10], av[11] - mv[11]);
        o1.z = pack2(av[12] - mv[12], av[13] - mv[13]);
        o1.w = pack2(av[14] - mv[14], av[15] - mv[15]);
        int byte = r * 640 + c * 32;
        int swz = (r & 7) << 4;
        *(uint4*)(sm + (byte ^ swz)) = o0;
        *(uint4*)(sm + ((byte + 16) ^ swz)) = o1;
    }
    __syncthreads();

    const int lane = tid & 63, wave = tid >> 6;   // wave = nt32 tile 0..9
    const int row = lane & 31, hi = lane >> 5;
    float16v acc;
#pragma unroll
    for (int q = 0; q < 16; ++q) acc[q] = 0.f;
    for (int kk = 0; kk < KKH32; ++kk) {
        int byte = row * 640 + kk * 32 + hi * 16;
        short8v a = *(const short8v*)(sm + (byte ^ ((row & 7) << 4)));
        short8v w = WhP[((kk * NT32 + wave) << 6) + lane];
        acc = __builtin_amdgcn_mfma_f32_32x32x16_bf16(w, a, acc, 0, 0, 0);
    }
    // epilogue: relu(acc + inp) -> fp8 tile (336B-padded rows, bank-spread)
#pragma unroll
    for (int q = 0; q < 4; ++q) {
        int colb = wave * 32 + q * 8 + hi * 4;
        uint2 u = *(const uint2*)(inp + (base + row) * HP + colb);
        float v0 = fmaxf(acc[4 * q + 0] + us2f(u.x & 0xffff), 0.f);
        float v1 = fmaxf(acc[4 * q + 1] + us2f(u.x >> 16), 0.f);
        float v2 = fmaxf(acc[4 * q + 2] + us2f(u.y & 0xffff), 0.f);
        float v3 = fmaxf(acc[4 * q + 3] + us2f(u.y >> 16), 0.f);
        *(u32*)(sm8 + row * 336 + colb) = f32x4_to_f8(v0, v1, v2, v3);
    }
    __syncthreads();
    {
        int r = tid / 20, c = tid % 20;
        uint4 v = *(const uint4*)(sm8 + r * 336 + c * 16);
        ((uint4*)(msgdst + (base + r) * 320))[c] = v;
    }
}

// ---------------------------------------------------------------------------
// K4G: ah = relu([amsg | f_atoms] @ Wo + b_o) (bf16, HP stride).
// 32 atoms/block, 640 threads = 10 waves, 32x32x16 MFMA, 28 K-steps.
__global__ __launch_bounds__(640, 8) void k4_gemm(const float* __restrict__ fa,
                                                  const u8* __restrict__ AM,
                                                  const short8v* __restrict__ WoP,
                                                  const float* __restrict__ bo,
                                                  u16* __restrict__ ah) {
    __shared__ __align__(16) char sm[32 * 896];    // stage; out tile reuses it
    const int tid = threadIdx.x;
    const long base = (long)blockIdx.x * 32;
    // amsg cols 0..299 (fp8 -> bf16): 32 rows x 19 chunks = 608 threads
    if (tid < 608) {
        int row = tid / 19, c = tid % 19;
        uint4 u = ((const uint4*)(AM + (base + row) * 320))[c];
        float v[16];
        f8x16_to_f32(u, v);
        uint4 o0, o1;
        o0.x = pack2(v[0], v[1]);  o0.y = pack2(v[2], v[3]);
        o0.z = pack2(v[4], v[5]);  o0.w = pack2(v[6], v[7]);
        o1.x = pack2(v[8], v[9]);  o1.y = pack2(v[10], v[11]);
        o1.z = pack2(v[12], v[13]); o1.w = pack2(v[14], v[15]);
        int byte = row * 896 + c * 32;
        int swz = (row & 7) << 4;
        *(uint4*)(sm + (byte ^ swz)) = o0;
        if (c < 18) {
            *(uint4*)(sm + ((byte + 16) ^ swz)) = o1;
        } else {  // cols 288..299: elems 8..11 only
            *(uint2*)(sm + ((byte + 16) ^ swz)) = make_uint2(o1.x, o1.y);
        }
    }
    // f_atoms cols 300..432 + pad to 448
    for (int i = tid; i < 32 * 148; i += 640) {
        int row = i / 148, c2 = i % 148;
        float v = (c2 < ATOM_FD) ? fa[(base + row) * ATOM_FD + c2] : 0.f;
        int byte = row * 896 + (HIDDEN + c2) * 2;
        *(u16*)(sm + (byte ^ ((row & 7) << 4))) = f2us(v);
    }
    __syncthreads();

    const int lane = tid & 63, wave = tid >> 6;   // wave = col tile 0..9
    const int row = lane & 31, hi = lane >> 5;
    float16v acc;
#pragma unroll
    for (int q = 0; q < 16; ++q) acc[q] = 0.f;
    for (int kk = 0; kk < KKO32; ++kk) {
        int byte = row * 896 + kk * 32 + hi * 16;
        short8v a = *(const short8v*)(sm + (byte ^ ((row & 7) << 4)));
        short8v w = WoP[((kk * NT32 + wave) << 6) + lane];
        acc = __builtin_amdgcn_mfma_f32_32x32x16_bf16(w, a, acc, 0, 0, 0);
    }
    __syncthreads();   // all ds_reads done before out-tile overwrites sm
#pragma unroll
    for (int q = 0; q < 4; ++q) {
        int colb = wave * 32 + q * 8 + hi * 4;
        float4v v;
#pragma unroll
        for (int d = 0; d < 4; ++d) {
            float bias = (colb + d < HIDDEN) ? bo[colb + d] : 0.f;
            v[d] = fmaxf(acc[4 * q + d] + bias, 0.f);
        }
        int byte = row * 640 + colb * 2;
        *(uint2*)(sm + (byte ^ ((row & 7) << 4))) = pack4(v);
    }
    __syncthreads();
#pragma unroll
    for (int it = 0; it < 2; ++it) {
        int i = tid + it * 640;
        if (i < 1280) {
            int r = i / CH, c = i % CH;
            int byte = r * 640 + c * 16;
            uint4 v = *(const uint4*)(sm + (byte ^ ((r & 7) << 4)));
            ((uint4*)(ah + (base + r) * HP))[c] = v;
        }
    }
}

// ---------------------------------------------------------------------------
// K5: mean-pool 20 contiguous atoms per molecule.
__global__ __launch_bounds__(320) void k5_pool(const u16* __restrict__ ah,
                                               float* __restrict__ out) {
    const int h = threadIdx.x;
    const int mol = blockIdx.x;
    if (h >= HIDDEN) return;
    float s = 0.f;
#pragma unroll
    for (int a = 0; a < APM; ++a)
        s += us2f(ah[((long)mol * APM + a) * HP + h]);
    out[(long)mol * HIDDEN + h] = s * (1.f / APM);
}

// ---------------------------------------------------------------------------
extern "C" void kernel_launch(void* const* d_in, const int* in_sizes, int n_in,
                              void* d_out, int out_size, void* d_ws, size_t ws_size,
                              hipStream_t stream) {
    const float* f_atoms = (const float*)d_in[0];
    const float* f_bonds = (const float*)d_in[1];
    const int* a2b = (const int*)d_in[2];
    const int* b2a = (const int*)d_in[3];
    const int* b2revb = (const int*)d_in[4];
    const float* Wi = (const float*)d_in[6];
    const float* Wh = (const float*)d_in[7];
    const float* Wo = (const float*)d_in[8];
    const float* bo = (const float*)d_in[9];
    float* out = (float*)d_out;

    char* ws = (char*)d_ws;
    size_t off = 0;
    auto alloc = [&](size_t bytes) {
        void* p = ws + off;
        off = (off + bytes + 255) & ~(size_t)255;
        return p;
    };
    u16* inp  = (u16*)alloc((size_t)N_BONDS * HP * sizeof(u16));  // 128 MB bf16
    u8* msgA  = (u8*)alloc((size_t)N_BONDS * 320);                //  64 MB fp8
    u8* msgB  = (u8*)alloc((size_t)N_BONDS * 320);                //  64 MB fp8
    u8* AM    = (u8*)alloc((size_t)N_ATOMS * 320);                //  32 MB fp8
    short* WiP32 = (short*)alloc((size_t)KKI32 * NT32 * 64 * 8 * sizeof(short));
    short* WhP32 = (short*)alloc((size_t)KKH32 * NT32 * 64 * 8 * sizeof(short));
    short* WoP32 = (short*)alloc((size_t)KKO32 * NT32 * 64 * 8 * sizeof(short));
    u16* ah = (u16*)msgA;   // msgA dead after iter-2 kzf; 100000*HP*2B = 64 MB fits

    pack_w32<<<KKI32 * NT32, 64, 0, stream>>>(Wi, WiP32, BOND_FD, 0);
    pack_w32<<<KKH32 * NT32, 64, 0, stream>>>(Wh, WhP32, HIDDEN, 0);
    pack_w32<<<KKO32 * NT32, 64, 0, stream>>>(Wo, WoP32, ATOM_FD + HIDDEN, 2);

    k1_input<<<N_BONDS / 32, 640, 0, stream>>>(f_bonds, (const short8v*)WiP32, inp);

    const int g2 = (N_ATOMS * 20 + 255) / 256;
    // iter 1: msg0 = relu(inp) applied on the fly (bf16 source)
    k2_gather<1><<<g2, 256, 0, stream>>>(inp, a2b, AM);
    kzf_update<1><<<N_BONDS / 32, 640, 0, stream>>>(inp, AM, inp, b2a, b2revb,
                                                    (const short8v*)WhP32, msgA);
    // iter 2 (fp8 sources)
    k2_gather<0><<<g2, 256, 0, stream>>>(msgA, a2b, AM);
    kzf_update<0><<<N_BONDS / 32, 640, 0, stream>>>(inp, AM, msgA, b2a, b2revb,
                                                    (const short8v*)WhP32, msgB);
    // readout: gather -> GEMM (ah reuses msgA) -> pool
    k2_gather<0><<<g2, 256, 0, stream>>>(msgB, a2b, AM);
    k4_gemm<<<N_ATOMS / 32 + 1, 640, 0, stream>>>(f_atoms, AM,
                                                  (const short8v*)WoP32, bo, ah);
    k5_pool<<<N_MOLS, 320, 0, stream>>>(ah, out);
}

// Round 12
// 495.208 us; speedup vs baseline: 1.9051x; 1.1104x over previous
//
#include <hip/hip_runtime.h>
#include <hip/hip_bf16.h>
#include <hip/hip_fp8.h>

#define N_ATOMS 100000
#define N_BONDS 200000
#define MAX_NB 6
#define HIDDEN 300
#define HP 320               // padded hidden: bf16 row = 640 B; fp8 row = 320 B
#define CH 40
#define ATOM_FD 133
#define BOND_FD 147
#define N_MOLS 5000
#define APM 20

#define NT32 10              // 32-col tiles
#define KKI32 10             // K=160 >= 147 in 16-steps
#define KKH32 20             // K=320 >= 300 in 16-steps
#define KKO32 28             // K=448 >= 433 in 16-steps

using bf16 = __hip_bfloat16;
typedef __attribute__((ext_vector_type(8))) short short8v;
typedef __attribute__((ext_vector_type(4))) float float4v;
typedef __attribute__((ext_vector_type(16))) float float16v;
typedef unsigned int u32;
typedef unsigned short u16;
typedef unsigned char u8;

__device__ __forceinline__ float us2f(u16 u) {
    union { u32 i; float f; } v; v.i = ((u32)u) << 16; return v.f;
}
__device__ __forceinline__ u16 f2us(float f) {
    bf16 h = __float2bfloat16(f);
    return *(u16*)&h;
}
__device__ __forceinline__ u32 pack2(float a, float b) {
    return (u32)f2us(a) | ((u32)f2us(b) << 16);
}
__device__ __forceinline__ uint2 pack4(const float4v& a) {
    uint2 o; o.x = pack2(a[0], a[1]); o.y = pack2(a[2], a[3]); return o;
}
__device__ __forceinline__ u32 relu2(u32 u) {
    u32 r = (u & 0x80000000u) ? (u & 0x0000ffffu) : u;
    r = (r & 0x8000u) ? (r & 0xffff0000u) : r;
    return r;
}
__device__ __forceinline__ uint4 relu8(uint4 u) {
    u.x = relu2(u.x); u.y = relu2(u.y); u.z = relu2(u.z); u.w = relu2(u.w);
    return u;
}

// ---- fp8 e4m3 (OCP on gfx950) conversion helpers -------------------------
#if defined(__has_builtin)
#if __has_builtin(__builtin_amdgcn_cvt_f32_fp8) && __has_builtin(__builtin_amdgcn_cvt_pk_fp8_f32)
#define HW_FP8 1
#endif
#endif

__device__ __forceinline__ void f8x4_to_f32(u32 p, float* o) {
#ifdef HW_FP8
    o[0] = __builtin_amdgcn_cvt_f32_fp8(p, 0);
    o[1] = __builtin_amdgcn_cvt_f32_fp8(p, 1);
    o[2] = __builtin_amdgcn_cvt_f32_fp8(p, 2);
    o[3] = __builtin_amdgcn_cvt_f32_fp8(p, 3);
#else
#pragma unroll
    for (int i = 0; i < 4; ++i) {
        __hip_fp8_e4m3 h; h.__x = (u8)(p >> (8 * i));
        o[i] = (float)h;
    }
#endif
}
__device__ __forceinline__ u32 f32x4_to_f8(float a, float b, float c, float d) {
#ifdef HW_FP8
    u32 r = __builtin_amdgcn_cvt_pk_fp8_f32(a, b, 0u, false);
    r = __builtin_amdgcn_cvt_pk_fp8_f32(c, d, r, true);
    return r;
#else
    __hip_fp8_e4m3 ha(a), hb(b), hc(c), hd(d);
    return (u32)ha.__x | ((u32)hb.__x << 8) | ((u32)hc.__x << 16) | ((u32)hd.__x << 24);
#endif
}
__device__ __forceinline__ void f8x16_to_f32(uint4 u, float* o) {
    f8x4_to_f32(u.x, o); f8x4_to_f32(u.y, o + 4);
    f8x4_to_f32(u.z, o + 8); f8x4_to_f32(u.w, o + 12);
}

// ---------------------------------------------------------------------------
// pack_w32: W [Ksrc x 300] fp32 -> 32x32x16 MFMA fragments [kk16][NT32][64][8]
// lane holds W[kk*16 + (l>>5)*8 + j][nt*32 + (l&31)].
// mode==2 (W_o): K layout is [amsg(0..299) | f_atoms(300..432)].
__global__ __launch_bounds__(64) void pack_w32(const float* __restrict__ src,
                                               short* __restrict__ dst,
                                               int Ksrc, int mode) {
    int kk = blockIdx.x / NT32, nt = blockIdx.x % NT32;
    int lane = threadIdx.x;
    int col = nt * 32 + (lane & 31);
#pragma unroll
    for (int j = 0; j < 8; ++j) {
        int k = kk * 16 + (lane >> 5) * 8 + j;
        float v = 0.f;
        if (k < Ksrc && col < HIDDEN) {
            int krow = k;
            if (mode == 2) krow = (k < HIDDEN) ? (ATOM_FD + k) : (k - HIDDEN);
            v = src[krow * HIDDEN + col];
        }
        dst[(((kk * NT32 + nt) << 6) + lane) * 8 + j] = (short)f2us(v);
    }
}

// ---------------------------------------------------------------------------
// K1: inp = f_bonds @ W_i (bf16 out). 32 rows/block, 320 threads = 5 waves,
// 2 col-tiles/wave; float4 flat staging; single 20KB LDS buffer (overlaid).
__global__ __launch_bounds__(320) void k1_input(const float* __restrict__ fb,
                                                const short8v* __restrict__ WiP,
                                                u16* __restrict__ inp) {
    __shared__ __align__(16) char sm[32 * 640];    // stage [32][320B] / out [32][640B]
    const int tid = threadIdx.x;
    const long base = (long)blockIdx.x * 32;
    // flat float4 staging: 32*147 = 4704 floats = 1176 float4 (16B-aligned)
    const float4* src4 = (const float4*)(fb + base * BOND_FD);
#pragma unroll
    for (int it = 0; it < 4; ++it) {
        int idx = tid + it * 320;
        if (idx < 1176) {
            float4 v = src4[idx];
            int f = idx * 4;
#pragma unroll
            for (int e = 0; e < 4; ++e) {
                int g = f + e;
                int r = g / BOND_FD, c = g - r * BOND_FD;
                int byte = r * 320 + c * 2;
                *(u16*)(sm + (byte ^ ((r & 7) << 4))) = f2us(((const float*)&v)[e]);
            }
        }
    }
    // zero pad cols 147..159
    for (int i = tid; i < 32 * 13; i += 320) {
        int r = i / 13, c = BOND_FD + i % 13;
        int byte = r * 320 + c * 2;
        *(u16*)(sm + (byte ^ ((r & 7) << 4))) = 0;
    }
    __syncthreads();

    const int lane = tid & 63, wave = tid >> 6;   // wave owns tiles 2w, 2w+1
    const int row = lane & 31, hi = lane >> 5;
    const int nt0 = wave * 2;
    float16v acc0, acc1;
#pragma unroll
    for (int q = 0; q < 16; ++q) { acc0[q] = 0.f; acc1[q] = 0.f; }
    for (int kk = 0; kk < KKI32; ++kk) {
        int byte = row * 320 + kk * 32 + hi * 16;
        short8v a = *(const short8v*)(sm + (byte ^ ((row & 7) << 4)));
        short8v w0 = WiP[((kk * NT32 + nt0) << 6) + lane];
        short8v w1 = WiP[((kk * NT32 + nt0 + 1) << 6) + lane];
        acc0 = __builtin_amdgcn_mfma_f32_32x32x16_bf16(w0, a, acc0, 0, 0, 0);
        acc1 = __builtin_amdgcn_mfma_f32_32x32x16_bf16(w1, a, acc1, 0, 0, 0);
    }
    __syncthreads();   // all stage reads done; overlay output tile
#pragma unroll
    for (int q = 0; q < 4; ++q) {
        float4v v0, v1;
#pragma unroll
        for (int d = 0; d < 4; ++d) { v0[d] = acc0[4 * q + d]; v1[d] = acc1[4 * q + d]; }
        int swz = (row & 7) << 4;
        int b0 = row * 640 + nt0 * 64 + q * 16 + hi * 8;
        int b1 = b0 + 64;
        *(uint2*)(sm + (b0 ^ swz)) = pack4(v0);
        *(uint2*)(sm + (b1 ^ swz)) = pack4(v1);
    }
    __syncthreads();
#pragma unroll
    for (int it = 0; it < 4; ++it) {
        int i = tid + it * 320;
        int r = i / CH, c = i % CH;
        int byte = r * 640 + c * 16;
        uint4 v = *(const uint4*)(sm + (byte ^ ((r & 7) << 4)));
        ((uint4*)(inp + (base + r) * HP))[c] = v;
    }
}

// ---------------------------------------------------------------------------
// K2G: AM[a] = fp8( sum_j act(src[a2b[a][j]]) ).  (unchanged)
template<int SRCBF>
__global__ __launch_bounds__(256, 8) void k2_gather(const void* __restrict__ srcv,
                                                    const int* __restrict__ a2b,
                                                    u8* __restrict__ dst) {
    int id = blockIdx.x * 256 + threadIdx.x;
    int atom = id / 20, c = id % 20;
    if (atom >= N_ATOMS) return;
    const int* nb = a2b + atom * MAX_NB;
    float s[16];
#pragma unroll
    for (int q = 0; q < 16; ++q) s[q] = 0.f;
#pragma unroll
    for (int j = 0; j < MAX_NB; ++j) {
        int b = nb[j];
        if (SRCBF) {
            const uint4* rp = (const uint4*)((const u16*)srcv + (long)b * HP);
            uint4 u0 = relu8(rp[2 * c]);
            uint4 u1 = relu8(rp[2 * c + 1]);
            s[0] += us2f(u0.x & 0xffff); s[1] += us2f(u0.x >> 16);
            s[2] += us2f(u0.y & 0xffff); s[3] += us2f(u0.y >> 16);
            s[4] += us2f(u0.z & 0xffff); s[5] += us2f(u0.z >> 16);
            s[6] += us2f(u0.w & 0xffff); s[7] += us2f(u0.w >> 16);
            s[8]  += us2f(u1.x & 0xffff); s[9]  += us2f(u1.x >> 16);
            s[10] += us2f(u1.y & 0xffff); s[11] += us2f(u1.y >> 16);
            s[12] += us2f(u1.z & 0xffff); s[13] += us2f(u1.z >> 16);
            s[14] += us2f(u1.w & 0xffff); s[15] += us2f(u1.w >> 16);
        } else {
            uint4 u = ((const uint4*)((const u8*)srcv + (long)b * 320))[c];
            float v[16];
            f8x16_to_f32(u, v);
#pragma unroll
            for (int q = 0; q < 16; ++q) s[q] += v[q];
        }
    }
    uint4 o;
    o.x = f32x4_to_f8(s[0], s[1], s[2], s[3]);
    o.y = f32x4_to_f8(s[4], s[5], s[6], s[7]);
    o.z = f32x4_to_f8(s[8], s[9], s[10], s[11]);
    o.w = f32x4_to_f8(s[12], s[13], s[14], s[15]);
    ((uint4*)(dst + (long)atom * 320))[c] = o;
}

// ---------------------------------------------------------------------------
// KZF: msg_out(fp8) = relu(inp + (AM[b2a] - act(msgsrc[b2revb])) @ W_h)
// 32 rows/block, 320 threads = 5 waves, 2 col-tiles/wave, 20KB LDS (overlaid).
template<int SRCBF>
__global__ __launch_bounds__(320) void kzf_update(const u16* __restrict__ inp,
                                                  const u8* __restrict__ AM,
                                                  const void* __restrict__ msgsrcv,
                                                  const int* __restrict__ b2a,
                                                  const int* __restrict__ b2revb,
                                                  const short8v* __restrict__ WhP,
                                                  u8* __restrict__ msgdst) {
    __shared__ __align__(16) char sm[32 * 640];    // bf16 m tile / fp8 out overlay
    const int tid = threadIdx.x;
    const long base = (long)blockIdx.x * 32;

    // stage: m = AM[b2a[r]] - act(msgsrc[b2revb[r]]), 2 chunks/thread
#pragma unroll
    for (int it = 0; it < 2; ++it) {
        int i = tid + it * 320;
        int r = i / 20, c = i % 20;
        long b = base + r;
        int ia = b2a[b], ir = b2revb[b];
        uint4 ua = ((const uint4*)(AM + (long)ia * 320))[c];
        float av[16];
        f8x16_to_f32(ua, av);
        float mv[16];
        if (SRCBF) {
            const uint4* rp = (const uint4*)((const u16*)msgsrcv + (long)ir * HP);
            uint4 u0 = relu8(rp[2 * c]);
            uint4 u1 = relu8(rp[2 * c + 1]);
            mv[0] = us2f(u0.x & 0xffff); mv[1] = us2f(u0.x >> 16);
            mv[2] = us2f(u0.y & 0xffff); mv[3] = us2f(u0.y >> 16);
            mv[4] = us2f(u0.z & 0xffff); mv[5] = us2f(u0.z >> 16);
            mv[6] = us2f(u0.w & 0xffff); mv[7] = us2f(u0.w >> 16);
            mv[8]  = us2f(u1.x & 0xffff); mv[9]  = us2f(u1.x >> 16);
            mv[10] = us2f(u1.y & 0xffff); mv[11] = us2f(u1.y >> 16);
            mv[12] = us2f(u1.z & 0xffff); mv[13] = us2f(u1.z >> 16);
            mv[14] = us2f(u1.w & 0xffff); mv[15] = us2f(u1.w >> 16);
        } else {
            uint4 um = ((const uint4*)((const u8*)msgsrcv + (long)ir * 320))[c];
            f8x16_to_f32(um, mv);
        }
        uint4 o0, o1;
        o0.x = pack2(av[0] - mv[0], av[1] - mv[1]);
        o0.y = pack2(av[2] - mv[2], av[3] - mv[3]);
        o0.z = pack2(av[4] - mv[4], av[5] - mv[5]);
        o0.w = pack2(av[6] - mv[6], av[7] - mv[7]);
        o1.x = pack2(av[8] - mv[8], av[9] - mv[9]);
        o1.y = pack2(av[10] - mv[10], av[11] - mv[11]);
        o1.z = pack2(av[12] - mv[12], av[13] - mv[13]);
        o1.w = pack2(av[14] - mv[14], av[15] - mv[15]);
        int byte = r * 640 + c * 32;
        int swz = (r & 7) << 4;
        *(uint4*)(sm + (byte ^ swz)) = o0;
        *(uint4*)(sm + ((byte + 16) ^ swz)) = o1;
    }
    __syncthreads();

    const int lane = tid & 63, wave = tid >> 6;
    const int row = lane & 31, hi = lane >> 5;
    const int nt0 = wave * 2;
    float16v acc0, acc1;
#pragma unroll
    for (int q = 0; q < 16; ++q) { acc0[q] = 0.f; acc1[q] = 0.f; }
    for (int kk = 0; kk < KKH32; ++kk) {
        int byte = row * 640 + kk * 32 + hi * 16;
        short8v a = *(const short8v*)(sm + (byte ^ ((row & 7) << 4)));
        short8v w0 = WhP[((kk * NT32 + nt0) << 6) + lane];
        short8v w1 = WhP[((kk * NT32 + nt0 + 1) << 6) + lane];
        acc0 = __builtin_amdgcn_mfma_f32_32x32x16_bf16(w0, a, acc0, 0, 0, 0);
        acc1 = __builtin_amdgcn_mfma_f32_32x32x16_bf16(w1, a, acc1, 0, 0, 0);
    }
    __syncthreads();   // stage reads done; overlay fp8 out tile [32][336B]
#pragma unroll
    for (int t = 0; t < 2; ++t) {
#pragma unroll
        for (int q = 0; q < 4; ++q) {
            int colb = (nt0 + t) * 32 + q * 8 + hi * 4;
            uint2 u = *(const uint2*)(inp + (base + row) * HP + colb);
            float a0 = (t == 0 ? acc0[4 * q + 0] : acc1[4 * q + 0]);
            float a1 = (t == 0 ? acc0[4 * q + 1] : acc1[4 * q + 1]);
            float a2 = (t == 0 ? acc0[4 * q + 2] : acc1[4 * q + 2]);
            float a3 = (t == 0 ? acc0[4 * q + 3] : acc1[4 * q + 3]);
            float v0 = fmaxf(a0 + us2f(u.x & 0xffff), 0.f);
            float v1 = fmaxf(a1 + us2f(u.x >> 16), 0.f);
            float v2 = fmaxf(a2 + us2f(u.y & 0xffff), 0.f);
            float v3 = fmaxf(a3 + us2f(u.y >> 16), 0.f);
            *(u32*)(sm + row * 336 + colb) = f32x4_to_f8(v0, v1, v2, v3);
        }
    }
    __syncthreads();
#pragma unroll
    for (int it = 0; it < 2; ++it) {
        int i = tid + it * 320;
        int r = i / 20, c = i % 20;
        uint4 v = *(const uint4*)(sm + r * 336 + c * 16);
        ((uint4*)(msgdst + (base + r) * 320))[c] = v;
    }
}

// ---------------------------------------------------------------------------
// K4G: ah = relu([amsg | f_atoms] @ Wo + b_o) (bf16, HP stride).
// 32 atoms/block, 640 threads = 10 waves, 32x32x16 MFMA, 28 K-steps.
__global__ __launch_bounds__(640, 8) void k4_gemm(const float* __restrict__ fa,
                                                  const u8* __restrict__ AM,
                                                  const short8v* __restrict__ WoP,
                                                  const float* __restrict__ bo,
                                                  u16* __restrict__ ah) {
    __shared__ __align__(16) char sm[32 * 896];    // stage; out tile reuses it
    const int tid = threadIdx.x;
    const long base = (long)blockIdx.x * 32;
    // amsg cols 0..299 (fp8 -> bf16): 32 rows x 19 chunks = 608 threads
    if (tid < 608) {
        int row = tid / 19, c = tid % 19;
        uint4 u = ((const uint4*)(AM + (base + row) * 320))[c];
        float v[16];
        f8x16_to_f32(u, v);
        uint4 o0, o1;
        o0.x = pack2(v[0], v[1]);  o0.y = pack2(v[2], v[3]);
        o0.z = pack2(v[4], v[5]);  o0.w = pack2(v[6], v[7]);
        o1.x = pack2(v[8], v[9]);  o1.y = pack2(v[10], v[11]);
        o1.z = pack2(v[12], v[13]); o1.w = pack2(v[14], v[15]);
        int byte = row * 896 + c * 32;
        int swz = (row & 7) << 4;
        *(uint4*)(sm + (byte ^ swz)) = o0;
        if (c < 18) {
            *(uint4*)(sm + ((byte + 16) ^ swz)) = o1;
        } else {  // cols 288..299: elems 8..11 only
            *(uint2*)(sm + ((byte + 16) ^ swz)) = make_uint2(o1.x, o1.y);
        }
    }
    // f_atoms cols 300..432 + pad to 448
    for (int i = tid; i < 32 * 148; i += 640) {
        int row = i / 148, c2 = i % 148;
        float v = (c2 < ATOM_FD) ? fa[(base + row) * ATOM_FD + c2] : 0.f;
        int byte = row * 896 + (HIDDEN + c2) * 2;
        *(u16*)(sm + (byte ^ ((row & 7) << 4))) = f2us(v);
    }
    __syncthreads();

    const int lane = tid & 63, wave = tid >> 6;   // wave = col tile 0..9
    const int row = lane & 31, hi = lane >> 5;
    float16v acc;
#pragma unroll
    for (int q = 0; q < 16; ++q) acc[q] = 0.f;
    for (int kk = 0; kk < KKO32; ++kk) {
        int byte = row * 896 + kk * 32 + hi * 16;
        short8v a = *(const short8v*)(sm + (byte ^ ((row & 7) << 4)));
        short8v w = WoP[((kk * NT32 + wave) << 6) + lane];
        acc = __builtin_amdgcn_mfma_f32_32x32x16_bf16(w, a, acc, 0, 0, 0);
    }
    __syncthreads();   // all ds_reads done before out-tile overwrites sm
#pragma unroll
    for (int q = 0; q < 4; ++q) {
        int colb = wave * 32 + q * 8 + hi * 4;
        float4v v;
#pragma unroll
        for (int d = 0; d < 4; ++d) {
            float bias = (colb + d < HIDDEN) ? bo[colb + d] : 0.f;
            v[d] = fmaxf(acc[4 * q + d] + bias, 0.f);
        }
        int byte = row * 640 + colb * 2;
        *(uint2*)(sm + (byte ^ ((row & 7) << 4))) = pack4(v);
    }
    __syncthreads();
#pragma unroll
    for (int it = 0; it < 2; ++it) {
        int i = tid + it * 640;
        if (i < 1280) {
            int r = i / CH, c = i % CH;
            int byte = r * 640 + c * 16;
            uint4 v = *(const uint4*)(sm + (byte ^ ((r & 7) << 4)));
            ((uint4*)(ah + (base + r) * HP))[c] = v;
        }
    }
}

// ---------------------------------------------------------------------------
// K5: mean-pool 20 contiguous atoms per molecule.
__global__ __launch_bounds__(320) void k5_pool(const u16* __restrict__ ah,
                                               float* __restrict__ out) {
    const int h = threadIdx.x;
    const int mol = blockIdx.x;
    if (h >= HIDDEN) return;
    float s = 0.f;
#pragma unroll
    for (int a = 0; a < APM; ++a)
        s += us2f(ah[((long)mol * APM + a) * HP + h]);
    out[(long)mol * HIDDEN + h] = s * (1.f / APM);
}

// ---------------------------------------------------------------------------
extern "C" void kernel_launch(void* const* d_in, const int* in_sizes, int n_in,
                              void* d_out, int out_size, void* d_ws, size_t ws_size,
                              hipStream_t stream) {
    const float* f_atoms = (const float*)d_in[0];
    const float* f_bonds = (const float*)d_in[1];
    const int* a2b = (const int*)d_in[2];
    const int* b2a = (const int*)d_in[3];
    const int* b2revb = (const int*)d_in[4];
    const float* Wi = (const float*)d_in[6];
    const float* Wh = (const float*)d_in[7];
    const float* Wo = (const float*)d_in[8];
    const float* bo = (const float*)d_in[9];
    float* out = (float*)d_out;

    char* ws = (char*)d_ws;
    size_t off = 0;
    auto alloc = [&](size_t bytes) {
        void* p = ws + off;
        off = (off + bytes + 255) & ~(size_t)255;
        return p;
    };
    u16* inp  = (u16*)alloc((size_t)N_BONDS * HP * sizeof(u16));  // 128 MB bf16
    u8* msgA  = (u8*)alloc((size_t)N_BONDS * 320);                //  64 MB fp8
    u8* msgB  = (u8*)alloc((size_t)N_BONDS * 320);                //  64 MB fp8
    u8* AM    = (u8*)alloc((size_t)N_ATOMS * 320);                //  32 MB fp8
    short* WiP32 = (short*)alloc((size_t)KKI32 * NT32 * 64 * 8 * sizeof(short));
    short* WhP32 = (short*)alloc((size_t)KKH32 * NT32 * 64 * 8 * sizeof(short));
    short* WoP32 = (short*)alloc((size_t)KKO32 * NT32 * 64 * 8 * sizeof(short));
    u16* ah = (u16*)msgA;   // msgA dead after iter-2 kzf; 64 MB fits

    pack_w32<<<KKI32 * NT32, 64, 0, stream>>>(Wi, WiP32, BOND_FD, 0);
    pack_w32<<<KKH32 * NT32, 64, 0, stream>>>(Wh, WhP32, HIDDEN, 0);
    pack_w32<<<KKO32 * NT32, 64, 0, stream>>>(Wo, WoP32, ATOM_FD + HIDDEN, 2);

    k1_input<<<N_BONDS / 32, 320, 0, stream>>>(f_bonds, (const short8v*)WiP32, inp);

    const int g2 = (N_ATOMS * 20 + 255) / 256;
    // iter 1: msg0 = relu(inp) applied on the fly (bf16 source)
    k2_gather<1><<<g2, 256, 0, stream>>>(inp, a2b, AM);
    kzf_update<1><<<N_BONDS / 32, 320, 0, stream>>>(inp, AM, inp, b2a, b2revb,
                                                    (const short8v*)WhP32, msgA);
    // iter 2 (fp8 sources)
    k2_gather<0><<<g2, 256, 0, stream>>>(msgA, a2b, AM);
    kzf_update<0><<<N_BONDS / 32, 320, 0, stream>>>(inp, AM, msgA, b2a, b2revb,
                                                    (const short8v*)WhP32, msgB);
    // readout: gather -> GEMM (ah reuses msgA) -> pool
    k2_gather<0><<<g2, 256, 0, stream>>>(msgB, a2b, AM);
    k4_gemm<<<N_ATOMS / 32, 640, 0, stream>>>(f_atoms, AM,
                                              (const short8v*)WoP32, bo, ah);
    k5_pool<<<N_MOLS, 320, 0, stream>>>(ah, out);
}

// Round 15
// 461.328 us; speedup vs baseline: 2.0450x; 1.0734x over previous
//
#include <hip/hip_runtime.h>
#include <hip/hip_bf16.h>
#include <hip/hip_fp8.h>

#define N_ATOMS 100000
#define N_BONDS 200000
#define MAX_NB 6
#define HIDDEN 300
#define HP 320               // padded hidden: bf16 row = 640 B; fp8 row = 320 B
#define CH 40
#define ATOM_FD 133
#define BOND_FD 147
#define N_MOLS 5000
#define APM 20

#define NT32 10              // 32-col tiles
#define KKI32 10             // K=160 >= 147 in 16-steps
#define KKH32 20             // K=320 >= 300 in 16-steps
#define KKO32 28             // K=448 >= 433 in 16-steps

using bf16 = __hip_bfloat16;
typedef __attribute__((ext_vector_type(8))) short short8v;
typedef __attribute__((ext_vector_type(4))) float float4v;
typedef __attribute__((ext_vector_type(16))) float float16v;
typedef unsigned int u32;
typedef unsigned short u16;
typedef unsigned char u8;

__device__ __forceinline__ float us2f(u16 u) {
    union { u32 i; float f; } v; v.i = ((u32)u) << 16; return v.f;
}
__device__ __forceinline__ u16 f2us(float f) {
    bf16 h = __float2bfloat16(f);
    return *(u16*)&h;
}
__device__ __forceinline__ u32 pack2(float a, float b) {
    return (u32)f2us(a) | ((u32)f2us(b) << 16);
}
__device__ __forceinline__ uint2 pack4(const float4v& a) {
    uint2 o; o.x = pack2(a[0], a[1]); o.y = pack2(a[2], a[3]); return o;
}
__device__ __forceinline__ u32 relu2(u32 u) {
    u32 r = (u & 0x80000000u) ? (u & 0x0000ffffu) : u;
    r = (r & 0x8000u) ? (r & 0xffff0000u) : r;
    return r;
}
__device__ __forceinline__ uint4 relu8(uint4 u) {
    u.x = relu2(u.x); u.y = relu2(u.y); u.z = relu2(u.z); u.w = relu2(u.w);
    return u;
}

// ---- fp8 e4m3 (OCP on gfx950) conversion helpers -------------------------
#if defined(__has_builtin)
#if __has_builtin(__builtin_amdgcn_cvt_f32_fp8) && __has_builtin(__builtin_amdgcn_cvt_pk_fp8_f32)
#define HW_FP8 1
#endif
#endif

__device__ __forceinline__ void f8x4_to_f32(u32 p, float* o) {
#ifdef HW_FP8
    o[0] = __builtin_amdgcn_cvt_f32_fp8(p, 0);
    o[1] = __builtin_amdgcn_cvt_f32_fp8(p, 1);
    o[2] = __builtin_amdgcn_cvt_f32_fp8(p, 2);
    o[3] = __builtin_amdgcn_cvt_f32_fp8(p, 3);
#else
#pragma unroll
    for (int i = 0; i < 4; ++i) {
        __hip_fp8_e4m3 h; h.__x = (u8)(p >> (8 * i));
        o[i] = (float)h;
    }
#endif
}
__device__ __forceinline__ u32 f32x4_to_f8(float a, float b, float c, float d) {
#ifdef HW_FP8
    u32 r = __builtin_amdgcn_cvt_pk_fp8_f32(a, b, 0u, false);
    r = __builtin_amdgcn_cvt_pk_fp8_f32(c, d, r, true);
    return r;
#else
    __hip_fp8_e4m3 ha(a), hb(b), hc(c), hd(d);
    return (u32)ha.__x | ((u32)hb.__x << 8) | ((u32)hc.__x << 16) | ((u32)hd.__x << 24);
#endif
}
__device__ __forceinline__ void f8x16_to_f32(uint4 u, float* o) {
    f8x4_to_f32(u.x, o); f8x4_to_f32(u.y, o + 4);
    f8x4_to_f32(u.z, o + 8); f8x4_to_f32(u.w, o + 12);
}

// ---------------------------------------------------------------------------
// pack_w32: W [Ksrc x 300] fp32 -> 32x32x16 MFMA fragments [kk16][NT32][64][8]
// lane holds W[kk*16 + (l>>5)*8 + j][nt*32 + (l&31)].
// mode==2 (W_o): K layout is [amsg(0..299) | f_atoms(300..432)].
__global__ __launch_bounds__(64) void pack_w32(const float* __restrict__ src,
                                               short* __restrict__ dst,
                                               int Ksrc, int mode) {
    int kk = blockIdx.x / NT32, nt = blockIdx.x % NT32;
    int lane = threadIdx.x;
    int col = nt * 32 + (lane & 31);
#pragma unroll
    for (int j = 0; j < 8; ++j) {
        int k = kk * 16 + (lane >> 5) * 8 + j;
        float v = 0.f;
        if (k < Ksrc && col < HIDDEN) {
            int krow = k;
            if (mode == 2) krow = (k < HIDDEN) ? (ATOM_FD + k) : (k - HIDDEN);
            v = src[krow * HIDDEN + col];
        }
        dst[(((kk * NT32 + nt) << 6) + lane) * 8 + j] = (short)f2us(v);
    }
}

// ---------------------------------------------------------------------------
// K1: inp = f_bonds @ W_i (bf16 out). 32 rows/block, 320 threads = 5 waves,
// 2 col-tiles/wave; float4 flat staging; single 20KB LDS buffer (overlaid).
__global__ __launch_bounds__(320) void k1_input(const float* __restrict__ fb,
                                                const short8v* __restrict__ WiP,
                                                u16* __restrict__ inp) {
    __shared__ __align__(16) char sm[32 * 640];    // stage [32][320B] / out [32][640B]
    const int tid = threadIdx.x;
    const long base = (long)blockIdx.x * 32;
    // flat float4 staging: 32*147 = 4704 floats = 1176 float4 (16B-aligned)
    const float4* src4 = (const float4*)(fb + base * BOND_FD);
#pragma unroll
    for (int it = 0; it < 4; ++it) {
        int idx = tid + it * 320;
        if (idx < 1176) {
            float4 v = src4[idx];
            int f = idx * 4;
#pragma unroll
            for (int e = 0; e < 4; ++e) {
                int g = f + e;
                int r = g / BOND_FD, c = g - r * BOND_FD;
                int byte = r * 320 + c * 2;
                *(u16*)(sm + (byte ^ ((r & 7) << 4))) = f2us(((const float*)&v)[e]);
            }
        }
    }
    // zero pad cols 147..159
    for (int i = tid; i < 32 * 13; i += 320) {
        int r = i / 13, c = BOND_FD + i % 13;
        int byte = r * 320 + c * 2;
        *(u16*)(sm + (byte ^ ((r & 7) << 4))) = 0;
    }
    __syncthreads();

    const int lane = tid & 63, wave = tid >> 6;   // wave owns tiles 2w, 2w+1
    const int row = lane & 31, hi = lane >> 5;
    const int nt0 = wave * 2;
    float16v acc0, acc1;
#pragma unroll
    for (int q = 0; q < 16; ++q) { acc0[q] = 0.f; acc1[q] = 0.f; }
    for (int kk = 0; kk < KKI32; ++kk) {
        int byte = row * 320 + kk * 32 + hi * 16;
        short8v a = *(const short8v*)(sm + (byte ^ ((row & 7) << 4)));
        short8v w0 = WiP[((kk * NT32 + nt0) << 6) + lane];
        short8v w1 = WiP[((kk * NT32 + nt0 + 1) << 6) + lane];
        acc0 = __builtin_amdgcn_mfma_f32_32x32x16_bf16(w0, a, acc0, 0, 0, 0);
        acc1 = __builtin_amdgcn_mfma_f32_32x32x16_bf16(w1, a, acc1, 0, 0, 0);
    }
    __syncthreads();   // all stage reads done; overlay output tile
#pragma unroll
    for (int q = 0; q < 4; ++q) {
        float4v v0, v1;
#pragma unroll
        for (int d = 0; d < 4; ++d) { v0[d] = acc0[4 * q + d]; v1[d] = acc1[4 * q + d]; }
        int swz = (row & 7) << 4;
        int b0 = row * 640 + nt0 * 64 + q * 16 + hi * 8;
        int b1 = b0 + 64;
        *(uint2*)(sm + (b0 ^ swz)) = pack4(v0);
        *(uint2*)(sm + (b1 ^ swz)) = pack4(v1);
    }
    __syncthreads();
#pragma unroll
    for (int it = 0; it < 4; ++it) {
        int i = tid + it * 320;
        int r = i / CH, c = i % CH;
        int byte = r * 640 + c * 16;
        uint4 v = *(const uint4*)(sm + (byte ^ ((r & 7) << 4)));
        ((uint4*)(inp + (base + r) * HP))[c] = v;
    }
}

// ---------------------------------------------------------------------------
// K2G: AM[a] = fp8( sum_j act(src[a2b[a][j]]) ).
// SRCBF=1: bf16 source (inp + relu), 1 chunk/thread.
// SRCBF=0: fp8 source, 2 contiguous chunks (32B)/thread — more MLP,
//          index loads amortized.
template<int SRCBF>
__global__ __launch_bounds__(256, 8) void k2_gather(const void* __restrict__ srcv,
                                                    const int* __restrict__ a2b,
                                                    u8* __restrict__ dst) {
    int id = blockIdx.x * 256 + threadIdx.x;
    if (SRCBF) {
        int atom = id / 20, c = id % 20;
        if (atom >= N_ATOMS) return;
        const int* nb = a2b + atom * MAX_NB;
        float s[16];
#pragma unroll
        for (int q = 0; q < 16; ++q) s[q] = 0.f;
#pragma unroll
        for (int j = 0; j < MAX_NB; ++j) {
            int b = nb[j];
            const uint4* rp = (const uint4*)((const u16*)srcv + (long)b * HP);
            uint4 u0 = relu8(rp[2 * c]);
            uint4 u1 = relu8(rp[2 * c + 1]);
            s[0] += us2f(u0.x & 0xffff); s[1] += us2f(u0.x >> 16);
            s[2] += us2f(u0.y & 0xffff); s[3] += us2f(u0.y >> 16);
            s[4] += us2f(u0.z & 0xffff); s[5] += us2f(u0.z >> 16);
            s[6] += us2f(u0.w & 0xffff); s[7] += us2f(u0.w >> 16);
            s[8]  += us2f(u1.x & 0xffff); s[9]  += us2f(u1.x >> 16);
            s[10] += us2f(u1.y & 0xffff); s[11] += us2f(u1.y >> 16);
            s[12] += us2f(u1.z & 0xffff); s[13] += us2f(u1.z >> 16);
            s[14] += us2f(u1.w & 0xffff); s[15] += us2f(u1.w >> 16);
        }
        uint4 o;
        o.x = f32x4_to_f8(s[0], s[1], s[2], s[3]);
        o.y = f32x4_to_f8(s[4], s[5], s[6], s[7]);
        o.z = f32x4_to_f8(s[8], s[9], s[10], s[11]);
        o.w = f32x4_to_f8(s[12], s[13], s[14], s[15]);
        ((uint4*)(dst + (long)atom * 320))[c] = o;
    } else {
        int atom = id / 10, c2 = id % 10;
        if (atom >= N_ATOMS) return;
        const int* nb = a2b + atom * MAX_NB;
        float s[32];
#pragma unroll
        for (int q = 0; q < 32; ++q) s[q] = 0.f;
#pragma unroll
        for (int j = 0; j < MAX_NB; ++j) {
            const uint4* rp = (const uint4*)((const u8*)srcv + (long)nb[j] * 320);
            uint4 u0 = rp[2 * c2];
            uint4 u1 = rp[2 * c2 + 1];
            float v[16];
            f8x16_to_f32(u0, v);
#pragma unroll
            for (int q = 0; q < 16; ++q) s[q] += v[q];
            f8x16_to_f32(u1, v);
#pragma unroll
            for (int q = 0; q < 16; ++q) s[16 + q] += v[q];
        }
        uint4 o0, o1;
        o0.x = f32x4_to_f8(s[0], s[1], s[2], s[3]);
        o0.y = f32x4_to_f8(s[4], s[5], s[6], s[7]);
        o0.z = f32x4_to_f8(s[8], s[9], s[10], s[11]);
        o0.w = f32x4_to_f8(s[12], s[13], s[14], s[15]);
        o1.x = f32x4_to_f8(s[16], s[17], s[18], s[19]);
        o1.y = f32x4_to_f8(s[20], s[21], s[22], s[23]);
        o1.z = f32x4_to_f8(s[24], s[25], s[26], s[27]);
        o1.w = f32x4_to_f8(s[28], s[29], s[30], s[31]);
        uint4* dp = (uint4*)(dst + (long)atom * 320);
        dp[2 * c2] = o0;
        dp[2 * c2 + 1] = o1;
    }
}

// ---------------------------------------------------------------------------
// KZF: msg_out(fp8) = relu(inp + (AM[b2a] - act(msgsrc[b2revb])) @ W_h)
// 32 rows/block, 320 threads = 5 waves, 2 col-tiles/wave, 20KB LDS (overlaid).
template<int SRCBF>
__global__ __launch_bounds__(320) void kzf_update(const u16* __restrict__ inp,
                                                  const u8* __restrict__ AM,
                                                  const void* __restrict__ msgsrcv,
                                                  const int* __restrict__ b2a,
                                                  const int* __restrict__ b2revb,
                                                  const short8v* __restrict__ WhP,
                                                  u8* __restrict__ msgdst) {
    __shared__ __align__(16) char sm[32 * 640];    // bf16 m tile / fp8 out overlay
    const int tid = threadIdx.x;
    const long base = (long)blockIdx.x * 32;

    // stage: m = AM[b2a[r]] - act(msgsrc[b2revb[r]]), 2 chunks/thread
#pragma unroll
    for (int it = 0; it < 2; ++it) {
        int i = tid + it * 320;
        int r = i / 20, c = i % 20;
        long b = base + r;
        int ia = b2a[b], ir = b2revb[b];
        uint4 ua = ((const uint4*)(AM + (long)ia * 320))[c];
        float av[16];
        f8x16_to_f32(ua, av);
        float mv[16];
        if (SRCBF) {
            const uint4* rp = (const uint4*)((const u16*)msgsrcv + (long)ir * HP);
            uint4 u0 = relu8(rp[2 * c]);
            uint4 u1 = relu8(rp[2 * c + 1]);
            mv[0] = us2f(u0.x & 0xffff); mv[1] = us2f(u0.x >> 16);
            mv[2] = us2f(u0.y & 0xffff); mv[3] = us2f(u0.y >> 16);
            mv[4] = us2f(u0.z & 0xffff); mv[5] = us2f(u0.z >> 16);
            mv[6] = us2f(u0.w & 0xffff); mv[7] = us2f(u0.w >> 16);
            mv[8]  = us2f(u1.x & 0xffff); mv[9]  = us2f(u1.x >> 16);
            mv[10] = us2f(u1.y & 0xffff); mv[11] = us2f(u1.y >> 16);
            mv[12] = us2f(u1.z & 0xffff); mv[13] = us2f(u1.z >> 16);
            mv[14] = us2f(u1.w & 0xffff); mv[15] = us2f(u1.w >> 16);
        } else {
            uint4 um = ((const uint4*)((const u8*)msgsrcv + (long)ir * 320))[c];
            f8x16_to_f32(um, mv);
        }
        uint4 o0, o1;
        o0.x = pack2(av[0] - mv[0], av[1] - mv[1]);
        o0.y = pack2(av[2] - mv[2], av[3] - mv[3]);
        o0.z = pack2(av[4] - mv[4], av[5] - mv[5]);
        o0.w = pack2(av[6] - mv[6], av[7] - mv[7]);
        o1.x = pack2(av[8] - mv[8], av[9] - mv[9]);
        o1.y = pack2(av[10] - mv[10], av[11] - mv[11]);
        o1.z = pack2(av[12] - mv[12], av[13] - mv[13]);
        o1.w = pack2(av[14] - mv[14], av[15] - mv[15]);
        int byte = r * 640 + c * 32;
        int swz = (r & 7) << 4;
        *(uint4*)(sm + (byte ^ swz)) = o0;
        *(uint4*)(sm + ((byte + 16) ^ swz)) = o1;
    }
    __syncthreads();

    const int lane = tid & 63, wave = tid >> 6;
    const int row = lane & 31, hi = lane >> 5;
    const int nt0 = wave * 2;
    float16v acc0, acc1;
#pragma unroll
    for (int q = 0; q < 16; ++q) { acc0[q] = 0.f; acc1[q] = 0.f; }
    for (int kk = 0; kk < KKH32; ++kk) {
        int byte = row * 640 + kk * 32 + hi * 16;
        short8v a = *(const short8v*)(sm + (byte ^ ((row & 7) << 4)));
        short8v w0 = WhP[((kk * NT32 + nt0) << 6) + lane];
        short8v w1 = WhP[((kk * NT32 + nt0 + 1) << 6) + lane];
        acc0 = __builtin_amdgcn_mfma_f32_32x32x16_bf16(w0, a, acc0, 0, 0, 0);
        acc1 = __builtin_amdgcn_mfma_f32_32x32x16_bf16(w1, a, acc1, 0, 0, 0);
    }
    __syncthreads();   // stage reads done; overlay fp8 out tile [32][336B]
#pragma unroll
    for (int t = 0; t < 2; ++t) {
#pragma unroll
        for (int q = 0; q < 4; ++q) {
            int colb = (nt0 + t) * 32 + q * 8 + hi * 4;
            uint2 u = *(const uint2*)(inp + (base + row) * HP + colb);
            float a0 = (t == 0 ? acc0[4 * q + 0] : acc1[4 * q + 0]);
            float a1 = (t == 0 ? acc0[4 * q + 1] : acc1[4 * q + 1]);
            float a2 = (t == 0 ? acc0[4 * q + 2] : acc1[4 * q + 2]);
            float a3 = (t == 0 ? acc0[4 * q + 3] : acc1[4 * q + 3]);
            float v0 = fmaxf(a0 + us2f(u.x & 0xffff), 0.f);
            float v1 = fmaxf(a1 + us2f(u.x >> 16), 0.f);
            float v2 = fmaxf(a2 + us2f(u.y & 0xffff), 0.f);
            float v3 = fmaxf(a3 + us2f(u.y >> 16), 0.f);
            *(u32*)(sm + row * 336 + colb) = f32x4_to_f8(v0, v1, v2, v3);
        }
    }
    __syncthreads();
#pragma unroll
    for (int it = 0; it < 2; ++it) {
        int i = tid + it * 320;
        int r = i / 20, c = i % 20;
        uint4 v = *(const uint4*)(sm + r * 336 + c * 16);
        ((uint4*)(msgdst + (base + r) * 320))[c] = v;
    }
}

// ---------------------------------------------------------------------------
// K4G: ah = relu([gathersum(msg) | f_atoms] @ Wo + b_o) (bf16, HP stride).
// Fused gather: stage computes sum_j msg[a2b[a,j]] (fp8) -> bf16 LDS directly.
// 32 atoms/block, 640 threads = 10 waves, 32x32x16 MFMA, 28 K-steps.
__global__ __launch_bounds__(640, 8) void k4_gemm(const float* __restrict__ fa,
                                                  const u8* __restrict__ msg,
                                                  const int* __restrict__ a2b,
                                                  const short8v* __restrict__ WoP,
                                                  const float* __restrict__ bo,
                                                  u16* __restrict__ ah) {
    __shared__ __align__(16) char sm[32 * 896];    // stage; out tile reuses it
    const int tid = threadIdx.x;
    const long base = (long)blockIdx.x * 32;
    // amsg cols 0..299: gather-sum 6 fp8 chunks -> bf16. 32 x 19 = 608 threads
    if (tid < 608) {
        int row = tid / 19, c = tid % 19;
        long atom = base + row;
        const int* nb = a2b + atom * MAX_NB;
        float s[16];
#pragma unroll
        for (int q = 0; q < 16; ++q) s[q] = 0.f;
#pragma unroll
        for (int j = 0; j < MAX_NB; ++j) {
            uint4 u = ((const uint4*)(msg + (long)nb[j] * 320))[c];
            float v[16];
            f8x16_to_f32(u, v);
#pragma unroll
            for (int q = 0; q < 16; ++q) s[q] += v[q];
        }
        uint4 o0, o1;
        o0.x = pack2(s[0], s[1]);  o0.y = pack2(s[2], s[3]);
        o0.z = pack2(s[4], s[5]);  o0.w = pack2(s[6], s[7]);
        o1.x = pack2(s[8], s[9]);  o1.y = pack2(s[10], s[11]);
        o1.z = pack2(s[12], s[13]); o1.w = pack2(s[14], s[15]);
        int byte = row * 896 + c * 32;
        int swz = (row & 7) << 4;
        *(uint4*)(sm + (byte ^ swz)) = o0;
        if (c < 18) {
            *(uint4*)(sm + ((byte + 16) ^ swz)) = o1;
        } else {  // cols 288..299: elems 8..11 only (12..15 overlap fa region)
            *(uint2*)(sm + ((byte + 16) ^ swz)) = make_uint2(o1.x, o1.y);
        }
    }
    // f_atoms cols 300..432: flat float4 (32*133 = 4256 floats = 1064 float4)
    const float4* src4 = (const float4*)(fa + base * ATOM_FD);
#pragma unroll
    for (int it = 0; it < 2; ++it) {
        int idx = tid + it * 640;
        if (idx < 1064) {
            float4 v = src4[idx];
            int f = idx * 4;
#pragma unroll
            for (int e = 0; e < 4; ++e) {
                int g = f + e;
                int r = g / ATOM_FD, c2 = g - r * ATOM_FD;
                int byte = r * 896 + (HIDDEN + c2) * 2;
                *(u16*)(sm + (byte ^ ((r & 7) << 4))) = f2us(((const float*)&v)[e]);
            }
        }
    }
    // zero pad cols 433..447 (32 rows x 15)
    if (tid < 480) {
        int r = tid / 15, c2 = ATOM_FD + tid % 15;
        int byte = r * 896 + (HIDDEN + c2) * 2;
        *(u16*)(sm + (byte ^ ((r & 7) << 4))) = 0;
    }
    __syncthreads();

    const int lane = tid & 63, wave = tid >> 6;   // wave = col tile 0..9
    const int row = lane & 31, hi = lane >> 5;
    float16v acc;
#pragma unroll
    for (int q = 0; q < 16; ++q) acc[q] = 0.f;
    for (int kk = 0; kk < KKO32; ++kk) {
        int byte = row * 896 + kk * 32 + hi * 16;
        short8v a = *(const short8v*)(sm + (byte ^ ((row & 7) << 4)));
        short8v w = WoP[((kk * NT32 + wave) << 6) + lane];
        acc = __builtin_amdgcn_mfma_f32_32x32x16_bf16(w, a, acc, 0, 0, 0);
    }
    __syncthreads();   // all ds_reads done before out-tile overwrites sm
#pragma unroll
    for (int q = 0; q < 4; ++q) {
        int colb = wave * 32 + q * 8 + hi * 4;
        float4v v;
#pragma unroll
        for (int d = 0; d < 4; ++d) {
            float bias = (colb + d < HIDDEN) ? bo[colb + d] : 0.f;
            v[d] = fmaxf(acc[4 * q + d] + bias, 0.f);
        }
        int byte = row * 640 + colb * 2;
        *(uint2*)(sm + (byte ^ ((row & 7) << 4))) = pack4(v);
    }
    __syncthreads();
#pragma unroll
    for (int it = 0; it < 2; ++it) {
        int i = tid + it * 640;
        if (i < 1280) {
            int r = i / CH, c = i % CH;
            int byte = r * 640 + c * 16;
            uint4 v = *(const uint4*)(sm + (byte ^ ((r & 7) << 4)));
            ((uint4*)(ah + (base + r) * HP))[c] = v;
        }
    }
}

// ---------------------------------------------------------------------------
// K5: mean-pool 20 contiguous atoms per molecule.
__global__ __launch_bounds__(320) void k5_pool(const u16* __restrict__ ah,
                                               float* __restrict__ out) {
    const int h = threadIdx.x;
    const int mol = blockIdx.x;
    if (h >= HIDDEN) return;
    float s = 0.f;
#pragma unroll
    for (int a = 0; a < APM; ++a)
        s += us2f(ah[((long)mol * APM + a) * HP + h]);
    out[(long)mol * HIDDEN + h] = s * (1.f / APM);
}

// ---------------------------------------------------------------------------
extern "C" void kernel_launch(void* const* d_in, const int* in_sizes, int n_in,
                              void* d_out, int out_size, void* d_ws, size_t ws_size,
                              hipStream_t stream) {
    const float* f_atoms = (const float*)d_in[0];
    const float* f_bonds = (const float*)d_in[1];
    const int* a2b = (const int*)d_in[2];
    const int* b2a = (const int*)d_in[3];
    const int* b2revb = (const int*)d_in[4];
    const float* Wi = (const float*)d_in[6];
    const float* Wh = (const float*)d_in[7];
    const float* Wo = (const float*)d_in[8];
    const float* bo = (const float*)d_in[9];
    float* out = (float*)d_out;

    char* ws = (char*)d_ws;
    size_t off = 0;
    auto alloc = [&](size_t bytes) {
        void* p = ws + off;
        off = (off + bytes + 255) & ~(size_t)255;
        return p;
    };
    u16* inp  = (u16*)alloc((size_t)N_BONDS * HP * sizeof(u16));  // 128 MB bf16
    u8* msgA  = (u8*)alloc((size_t)N_BONDS * 320);                //  64 MB fp8
    u8* msgB  = (u8*)alloc((size_t)N_BONDS * 320);                //  64 MB fp8
    u8* AM    = (u8*)alloc((size_t)N_ATOMS * 320);                //  32 MB fp8
    short* WiP32 = (short*)alloc((size_t)KKI32 * NT32 * 64 * 8 * sizeof(short));
    short* WhP32 = (short*)alloc((size_t)KKH32 * NT32 * 64 * 8 * sizeof(short));
    short* WoP32 = (short*)alloc((size_t)KKO32 * NT32 * 64 * 8 * sizeof(short));
    u16* ah = (u16*)msgA;   // msgA dead after iter-2 kzf; 64 MB fits

    pack_w32<<<KKI32 * NT32, 64, 0, stream>>>(Wi, WiP32, BOND_FD, 0);
    pack_w32<<<KKH32 * NT32, 64, 0, stream>>>(Wh, WhP32, HIDDEN, 0);
    pack_w32<<<KKO32 * NT32, 64, 0, stream>>>(Wo, WoP32, ATOM_FD + HIDDEN, 2);

    k1_input<<<N_BONDS / 32, 320, 0, stream>>>(f_bonds, (const short8v*)WiP32, inp);

    // iter 1: msg0 = relu(inp) applied on the fly (bf16 source)
    const int g2a = (N_ATOMS * 20 + 255) / 256;
    k2_gather<1><<<g2a, 256, 0, stream>>>(inp, a2b, AM);
    kzf_update<1><<<N_BONDS / 32, 320, 0, stream>>>(inp, AM, inp, b2a, b2revb,
                                                    (const short8v*)WhP32, msgA);
    // iter 2 (fp8 sources, 2-chunk gather)
    const int g2b = (N_ATOMS * 10 + 255) / 256;
    k2_gather<0><<<g2b, 256, 0, stream>>>(msgA, a2b, AM);
    kzf_update<0><<<N_BONDS / 32, 320, 0, stream>>>(inp, AM, msgA, b2a, b2revb,
                                                    (const short8v*)WhP32, msgB);
    // readout: fused gather-GEMM (ah reuses msgA) -> pool
    k4_gemm<<<N_ATOMS / 32, 640, 0, stream>>>(f_atoms, msgB, a2b,
                                              (const short8v*)WoP32, bo, ah);
    k5_pool<<<N_MOLS, 320, 0, stream>>>(ah, out);
}